// Round 1
// 755.338 us; speedup vs baseline: 1.0151x; 1.0151x over previous
//
#include <hip/hip_runtime.h>
#include <hip/hip_bf16.h>

typedef __attribute__((ext_vector_type(8))) short short8;
typedef __attribute__((ext_vector_type(4))) float f32x4;
typedef __attribute__((ext_vector_type(4))) unsigned short us4;

#define DEV static __device__ __forceinline__

constexpr int QLEN = 2048;
constexpr int DMODEL = 4096;
constexpr int NHEAD = 32;
constexpr int NKV = 8;
constexpr int HD = 128;
constexpr int NSINK = 4;
constexpr int NWIN = 2048;
constexpr int CUR0 = NSINK + NWIN;     // 2052
constexpr int KTOT = CUR0 + QLEN;      // 4100
constexpr int KT_PAD = 4224;           // 66 * 64
constexpr float LOG2E = 1.4426950408889634f;
constexpr float NEGBIG = -1.0e30f;
constexpr float MSHIFT = 32.0f;        // fixed softmax shift (log2 units)
constexpr float QSCALE = 0.08838834764831843f * LOG2E; // 1/sqrt(128) * log2(e)

DEV unsigned short f2bf(float f) {
  unsigned int u = __float_as_uint(f);
  u += 0x7fffu + ((u >> 16) & 1u);
  return (unsigned short)(u >> 16);
}

DEV unsigned int pk2(float a, float b) {   // packed bf16 pair, RNE (v_cvt_pk_bf16_f32)
  __hip_bfloat162 h = __float22bfloat162_rn(make_float2(a, b));
  return *(unsigned int*)&h;
}

DEV void gld16(const void* g, void* l) {
  __builtin_amdgcn_global_load_lds((const __attribute__((address_space(1))) void*)g,
                                   (__attribute__((address_space(3))) void*)l, 16, 0, 0);
}

// ---------------- small prep kernels ----------------

__global__ void maxpos_kernel(const int* __restrict__ sp, const int* __restrict__ kp,
                              int* __restrict__ outp) {
  __shared__ int red[256];
  int t = threadIdx.x;
  int m = -0x7fffffff;
  for (int i = t; i < NSINK; i += 256) m = max(m, sp[i]);
  for (int i = t; i < NWIN; i += 256) m = max(m, kp[i]);
  red[t] = m;
  __syncthreads();
  for (int s = 128; s > 0; s >>= 1) {
    if (t < s) red[t] = max(red[t], red[t + s]);
    __syncthreads();
  }
  if (t == 0) outp[0] = red[0] + 1;
}

__global__ void bias_kernel(const float* __restrict__ sm, const float* __restrict__ km,
                            float* __restrict__ bias) {
  int kk = blockIdx.x * 256 + threadIdx.x;
  if (kk >= KT_PAD) return;
  float b;
  if (kk < NSINK) b = sm[kk] * NEGBIG * LOG2E - MSHIFT;
  else if (kk < CUR0) b = km[kk - NSINK] * NEGBIG * LOG2E - MSHIFT;
  else if (kk < KTOT) b = -MSHIFT;
  else b = NEGBIG;
  bias[kk] = b;
}

// cos/sin table for query positions: tab[q][j] = (cos,sin)((maxp+q) * invf(j))
__global__ void postab_kernel(const int* __restrict__ maxp, float2* __restrict__ tab) {
  int q = blockIdx.x, j = threadIdx.x;
  float pos = (float)(maxp[0] + q);
  float invf = exp2f(-(float)(2 * j) * (13.287712379549449f / 128.0f));
  float ang = pos * invf;
  tab[q * 64 + j] = make_float2(__cosf(ang), __sinf(ang));
}

__global__ __launch_bounds__(256) void cvt_kernel(const float* __restrict__ src,
                                                  unsigned short* __restrict__ dst) {
  long i = ((long)blockIdx.x * 256 + threadIdx.x) * 4;
  f32x4 v = *(const f32x4*)(src + i);
  us4 o;
  o[0] = f2bf(v[0]); o[1] = f2bf(v[1]); o[2] = f2bf(v[2]); o[3] = f2bf(v[3]);
  *(us4*)(dst + i) = o;
}

// all 4 weight transposes in one launch. x: [0,128)=Wq [128,160)=Wk [160,192)=Wv [192,320)=Wo
__global__ void transpose_all(const float* __restrict__ Wq, const float* __restrict__ Wk,
                              const float* __restrict__ Wv, const float* __restrict__ Wo,
                              unsigned short* __restrict__ WqkvT,
                              unsigned short* __restrict__ WoT) {
  __shared__ float t[32][33];
  int bx = blockIdx.x;
  const float* W; unsigned short* WT; int N; int xl;
  if (bx < 128)      { W = Wq; WT = WqkvT;                   N = 4096; xl = bx; }
  else if (bx < 160) { W = Wk; WT = WqkvT + 4096L * 4096;    N = 1024; xl = bx - 128; }
  else if (bx < 192) { W = Wv; WT = WqkvT + 5120L * 4096;    N = 1024; xl = bx - 160; }
  else               { W = Wo; WT = WoT;                     N = 4096; xl = bx - 192; }
  int n0 = xl * 32, k0 = blockIdx.y * 32;
  int tx = threadIdx.x, ty = threadIdx.y;
  for (int p = 0; p < 4; p++) {
    int k = k0 + ty + p * 8;
    t[ty + p * 8][tx] = W[(long)k * N + n0 + tx];
  }
  __syncthreads();
  for (int p = 0; p < 4; p++) {
    int n = n0 + ty + p * 8;
    WT[(long)n * 4096 + k0 + tx] = f2bf(t[tx][ty + p * 8]);
  }
}

// ---------------- generic GEMM (used for output projection, f32 C) ----------------
__global__ __launch_bounds__(256) void gemm_bt(const unsigned short* __restrict__ A,
                                               const unsigned short* __restrict__ Bt,
                                               float* __restrict__ C,
                                               int M, int N, int K) {
  __shared__ __align__(16) unsigned short As[128 * 64];
  __shared__ __align__(16) unsigned short Bs[128 * 64];
  int tid = threadIdx.x, lane = tid & 63, w = tid >> 6;
  int m0 = blockIdx.y * 128, n0 = blockIdx.x * 128;
  int wm = w & 1, wn = w >> 1;
  f32x4 z = {0.f, 0.f, 0.f, 0.f};
  f32x4 acc[4][4];
  for (int i = 0; i < 4; i++) for (int j = 0; j < 4; j++) acc[i][j] = z;
  int nK = K >> 6;
  for (int ks = 0; ks < nK; ks++) {
    long k0 = (long)ks << 6;
    for (int t = 0; t < 4; t++) {
      int chunk = w * 4 + t;
      int row = chunk * 8 + (lane >> 3);
      int kbs = (lane & 7) ^ (row & 7);
      gld16(A + ((long)(m0 + row) * K + k0 + kbs * 8), &As[chunk * 512 + lane * 8]);
      gld16(Bt + ((long)(n0 + row) * K + k0 + kbs * 8), &Bs[chunk * 512 + lane * 8]);
    }
    __syncthreads();
    for (int kc = 0; kc < 2; kc++) {
      short8 af[4], bf[4];
      int c = kc * 4 + (lane >> 4);
      for (int i = 0; i < 4; i++) {
        int ra = wm * 64 + i * 16 + (lane & 15);
        af[i] = *(const short8*)&As[ra * 64 + (c ^ (ra & 7)) * 8];
        int rb = wn * 64 + i * 16 + (lane & 15);
        bf[i] = *(const short8*)&Bs[rb * 64 + (c ^ (rb & 7)) * 8];
      }
      for (int i = 0; i < 4; i++)
        for (int j = 0; j < 4; j++)
          acc[i][j] = __builtin_amdgcn_mfma_f32_16x16x32_bf16(af[i], bf[j], acc[i][j], 0, 0, 0);
    }
    __syncthreads();
  }
  for (int i = 0; i < 4; i++) {
    int m = m0 + wm * 64 + i * 16 + ((lane >> 4) << 2);
    for (int j = 0; j < 4; j++) {
      int n = n0 + wn * 64 + j * 16 + (lane & 15);
      float* cp = C + (long)m * N + n;
      for (int r = 0; r < 4; r++) cp[(long)r * N] = acc[i][j][r];
    }
  }
}

// ---------------- fused QKV GEMM + RoPE + scatter epilogue ----------------
// A=[2048][4096] bf16, Bt=[6144][4096] bf16. C-tile 128x128 aligns with heads:
// nb<32 -> Q head nb (rope, *QSCALE -> Qb); nb in[32,40) -> K-cur kvh nb-32
// (rope -> Kb at CUR0+); nb>=40 -> V kvh nb-40 (transpose -> VTb at CUR0+).
__global__ __launch_bounds__(256) void gemm_qkv(const unsigned short* __restrict__ A,
                                                const unsigned short* __restrict__ Bt,
                                                const float2* __restrict__ postab,
                                                unsigned short* __restrict__ Qb,
                                                unsigned short* __restrict__ Kb,
                                                unsigned short* __restrict__ VTb) {
  __shared__ __align__(16) char smem[66 * 512];           // 33 KB: staging / epilogue union
  unsigned short* As = (unsigned short*)smem;             // 16 KB
  unsigned short* Bs = As + 8192;                         // 16 KB
  float* Cs = (float*)smem;                               // 64 x 129 f32 = 33024 B
  constexpr int K = 4096;
  int tid = threadIdx.x, lane = tid & 63, w = tid >> 6;
  int quad = lane >> 4, l15 = lane & 15;
  int m0 = blockIdx.y * 128, n0 = blockIdx.x * 128;
  int wm = w & 1, wn = w >> 1;
  f32x4 z = {0.f, 0.f, 0.f, 0.f};
  f32x4 acc[4][4];
  for (int i = 0; i < 4; i++) for (int j = 0; j < 4; j++) acc[i][j] = z;
  for (int ks = 0; ks < K / 64; ks++) {
    long k0 = (long)ks << 6;
    for (int t = 0; t < 4; t++) {
      int chunk = w * 4 + t;
      int row = chunk * 8 + (lane >> 3);
      int kbs = (lane & 7) ^ (row & 7);
      gld16(A + ((long)(m0 + row) * K + k0 + kbs * 8), &As[chunk * 512 + lane * 8]);
      gld16(Bt + ((long)(n0 + row) * K + k0 + kbs * 8), &Bs[chunk * 512 + lane * 8]);
    }
    __syncthreads();
    for (int kc = 0; kc < 2; kc++) {
      short8 af[4], bf[4];
      int c = kc * 4 + quad;
      for (int i = 0; i < 4; i++) {
        int ra = wm * 64 + i * 16 + l15;
        af[i] = *(const short8*)&As[ra * 64 + (c ^ (ra & 7)) * 8];
        int rb = wn * 64 + i * 16 + l15;
        bf[i] = *(const short8*)&Bs[rb * 64 + (c ^ (rb & 7)) * 8];
      }
      for (int i = 0; i < 4; i++)
        for (int j = 0; j < 4; j++)
          acc[i][j] = __builtin_amdgcn_mfma_f32_16x16x32_bf16(af[i], bf[j], acc[i][j], 0, 0, 0);
    }
    __syncthreads();
  }

  int nb = blockIdx.x;
  int part = (nb < 32) ? 0 : (nb < 40 ? 1 : 2);
  int hh = (part == 0) ? nb : (part == 1 ? nb - 32 : nb - 40);
  float scale = (part == 0) ? QSCALE : 1.0f;

  for (int pass = 0; pass < 2; pass++) {
    __syncthreads();
    if (wm == pass) {
      for (int i = 0; i < 4; i++)
        for (int j = 0; j < 4; j++)
          for (int r = 0; r < 4; r++)
            Cs[(i * 16 + quad * 4 + r) * 129 + wn * 64 + j * 16 + l15] = acc[i][j][r];
    }
    __syncthreads();
    if (part < 2) {
      if (tid < 128) {
        int r = tid & 63, hf = tid >> 6;
        int query = m0 + pass * 64 + r;
        const float2* tb = postab + query * 64;
        unsigned short* dst = (part == 0)
            ? Qb + ((long)hh * QLEN + query) * HD + hf * 64
            : Kb + ((long)hh * KT_PAD + CUR0 + query) * HD + hf * 64;
        for (int j = 0; j < 64; j += 4) {
          float v[4];
          for (int u = 0; u < 4; u++) {
            float2 cs = tb[j + u];
            int d = hf * 64 + j + u;
            float xa = Cs[r * 129 + d];
            float xb = Cs[r * 129 + (d ^ 64)];
            v[u] = (xa * cs.x + (hf ? xb : -xb) * cs.y) * scale;
          }
          uint2 o4;
          o4.x = pk2(v[0], v[1]);
          o4.y = pk2(v[2], v[3]);
          *(uint2*)(dst + j) = o4;
        }
      }
    } else {
      if (tid < 128) {
        int d = tid;
        unsigned short* dst = VTb + ((long)hh * HD + d) * KT_PAD + CUR0 + m0 + pass * 64;
        for (int m = 0; m < 64; m += 4) {
          uint2 o4;
          o4.x = pk2(Cs[m * 129 + d], Cs[(m + 1) * 129 + d]);
          o4.y = pk2(Cs[(m + 2) * 129 + d], Cs[(m + 3) * 129 + d]);
          *(uint2*)(dst + m) = o4;
        }
      }
    }
  }
}

// ---------------- cache (sink + window) RoPE / V scatter ----------------
__global__ void rope_cache(const float* __restrict__ sink_k, const float* __restrict__ win_k,
                           const int* __restrict__ sp, const int* __restrict__ kp,
                           unsigned short* __restrict__ Kb) {
  int s = blockIdx.x, kvh = blockIdx.y, d = threadIdx.x;
  const float* src; int pos;
  if (s < NSINK) { src = sink_k + ((long)kvh * NSINK + s) * HD; pos = sp[s]; }
  else           { src = win_k + ((long)kvh * NWIN + (s - NSINK)) * HD; pos = kp[s - NSINK]; }
  float x = src[d];
  float x2 = src[d ^ 64];
  float rot = (d < 64) ? -x2 : x2;
  int i = d & 63;
  float invf = exp2f(-(float)(2 * i) * (13.287712379549449f / 128.0f));
  float ang = (float)pos * invf;
  float c = __cosf(ang), sn = __sinf(ang);
  Kb[((long)kvh * KT_PAD + s) * HD + d] = f2bf(x * c + rot * sn);
}

// x<64: window chunk; x==64: sinks
__global__ void scatter_cache(const float* __restrict__ sink_v, const float* __restrict__ win_v,
                              unsigned short* __restrict__ VTb) {
  __shared__ float t[32][33];
  int kvh = blockIdx.z, d0 = blockIdx.y * 32;
  const float* src; int S, s0, dstPos0;
  if (blockIdx.x < 64) { src = win_v + (long)kvh * NWIN * HD; S = NWIN; s0 = blockIdx.x * 32; dstPos0 = NSINK; }
  else                 { src = sink_v + (long)kvh * NSINK * HD; S = NSINK; s0 = 0; dstPos0 = 0; }
  int tx = threadIdx.x, ty = threadIdx.y;
  for (int p = 0; p < 4; p++) {
    int s = s0 + ty + p * 8;
    if (s < S) t[ty + p * 8][tx] = src[(long)s * HD + d0 + tx];
  }
  __syncthreads();
  for (int p = 0; p < 4; p++) {
    int d = d0 + ty + p * 8;
    int s = s0 + tx;
    if (s < S)
      VTb[((long)kvh * HD + d) * KT_PAD + dstPos0 + s] = f2bf(t[tx][ty + p * 8]);
  }
}

__global__ void pad_zero(unsigned short* __restrict__ Kb, unsigned short* __restrict__ VTb) {
  int idx = blockIdx.x * 256 + threadIdx.x;
  int total = NKV * (KT_PAD - KTOT) * HD;
  if (idx >= total) return;
  int per = (KT_PAD - KTOT) * HD;
  int kvh = idx / per;
  int rem = idx % per;
  int pos = KTOT + rem / HD;
  int d = rem % HD;
  Kb[((long)kvh * KT_PAD + pos) * HD + d] = 0;
  VTb[((long)kvh * HD + d) * KT_PAD + pos] = 0;
}

// ---------------- flash attention (S^T, fixed-shift softmax, dbuf, XCD-mapped) ----
DEV void stage_kv(const unsigned short* __restrict__ Kbase,
                  const unsigned short* __restrict__ Vbase, long k0,
                  unsigned short* KtB, unsigned short* VtB, int w, int lane) {
  int quad = lane >> 4, l15 = lane & 15;
  for (int t = 0; t < 4; t++) {
    int chunk = w * 4 + t;
    { int row = chunk * 4 + quad;
      int kbs = l15 ^ (row & 15);
      gld16(Kbase + (k0 + row) * HD + kbs * 8, &KtB[chunk * 512 + lane * 8]); }
    { int row = chunk * 8 + (lane >> 3);
      int kbs = (lane & 7) ^ (row & 7);
      gld16(Vbase + (long)row * KT_PAD + k0 + kbs * 8, &VtB[chunk * 512 + lane * 8]); }
  }
}

__global__ __launch_bounds__(256) void attn_kernel(
    const unsigned short* __restrict__ Qb,
    const unsigned short* __restrict__ Kb,
    const unsigned short* __restrict__ VTb,
    const float* __restrict__ biasArr,
    unsigned short* __restrict__ attnOut) {
  __shared__ __align__(16) unsigned short Kt[2][64 * 128];
  __shared__ __align__(16) unsigned short Vt[2][128 * 64];
  __shared__ __align__(16) unsigned short Pl[4][16 * 72];
  __shared__ float abuf[4][2][16];
  int tid = threadIdx.x, lane = tid & 63, w = tid >> 6;
  int quad = lane >> 4, l15 = lane & 15;
  int hh = blockIdx.x;
  int h = (hh & 7) * 4 + (hh >> 3);
  int kvh = hh & 7;
  int yt = blockIdx.y;
  int qt = (yt < 8) ? yt : (23 - yt);
  int q0 = qt * 128;
  int wq0 = q0 + w * 32;

  short8 qf[2][4];
  for (int g = 0; g < 2; g++)
    for (int kc = 0; kc < 4; kc++) {
      long off = ((long)h * QLEN + wq0 + g * 16 + l15) * HD + kc * 32 + quad * 8;
      qf[g][kc] = *(const short8*)(Qb + off);
    }

  f32x4 z = {0.f, 0.f, 0.f, 0.f};
  f32x4 o[2][8];
  for (int g = 0; g < 2; g++) for (int j = 0; j < 8; j++) o[g][j] = z;
  float lrun[2] = {0.f, 0.f};

  int nsteps = min(KT_PAD / 64, (CUR0 + q0 + 127) / 64 + 1);
  const unsigned short* Kbase = Kb + (long)kvh * KT_PAD * HD;
  const unsigned short* Vbase = VTb + (long)kvh * HD * KT_PAD;

  stage_kv(Kbase, Vbase, 0, Kt[0], Vt[0], w, lane);

  for (int st = 0; st < nsteps; st++) {
    long k0 = (long)st * 64;
    int cur = st & 1;
    __syncthreads();

    f32x4 b4[4];
    for (int t = 0; t < 4; t++)
      b4[t] = *(const f32x4*)&biasArr[k0 + 16 * t + quad * 4];

    if (st + 1 < nsteps)
      stage_kv(Kbase, Vbase, k0 + 64, Kt[cur ^ 1], Vt[cur ^ 1], w, lane);

    const unsigned short* KtB = Kt[cur];
    const unsigned short* VtB = Vt[cur];

    f32x4 stt[2][4];
    for (int g = 0; g < 2; g++) for (int t = 0; t < 4; t++) stt[g][t] = z;
    __builtin_amdgcn_s_setprio(1);
    for (int kc = 0; kc < 4; kc++) {
      for (int t = 0; t < 4; t++) {
        int row = 16 * t + l15;
        short8 kf = *(const short8*)&KtB[row * 128 + (((kc * 4 + quad) ^ (row & 15))) * 8];
        stt[0][t] = __builtin_amdgcn_mfma_f32_16x16x32_bf16(kf, qf[0][kc], stt[0][t], 0, 0, 0);
        stt[1][t] = __builtin_amdgcn_mfma_f32_16x16x32_bf16(kf, qf[1][kc], stt[1][t], 0, 0, 0);
      }
    }
    __builtin_amdgcn_s_setprio(0);

    // softmax for both query groups first (Pl reused sequentially within the
    // wave; lgkmcnt ordering makes write->read safe), then one fused PV pass
    // that reads each V fragment ONCE and feeds both accumulator groups.
    bool act0 = ((int)k0 <= wq0 + 15 + CUR0);
    bool act1 = ((int)k0 <= wq0 + 31 + CUR0);
    short8 pf[2][2];
    for (int g = 0; g < 2; g++) {
      if (!(g ? act1 : act0)) continue;
      int query = wq0 + g * 16 + l15;
      bool needMask = (int)k0 + 63 > wq0 + g * 16 + CUR0;
      float ps = 0.f;
      if (needMask) {
        for (int t = 0; t < 4; t++) {
          float p[4];
          for (int r = 0; r < 4; r++) {
            int key = (int)k0 + 16 * t + quad * 4 + r;
            float v = stt[g][t][r] + b4[t][r];
            if (key > query + CUR0) v = NEGBIG;
            p[r] = exp2f(v);
            ps += p[r];
          }
          uint2 pw;
          pw.x = pk2(p[0], p[1]);
          pw.y = pk2(p[2], p[3]);
          *(uint2*)&Pl[w][l15 * 72 + 16 * t + quad * 4] = pw;
        }
      } else {
        for (int t = 0; t < 4; t++) {
          float p[4];
          for (int r = 0; r < 4; r++) {
            p[r] = exp2f(stt[g][t][r] + b4[t][r]);
            ps += p[r];
          }
          uint2 pw;
          pw.x = pk2(p[0], p[1]);
          pw.y = pk2(p[2], p[3]);
          *(uint2*)&Pl[w][l15 * 72 + 16 * t + quad * 4] = pw;
        }
      }
      lrun[g] += ps;
      pf[g][0] = *(const short8*)&Pl[w][l15 * 72 + quad * 8];
      pf[g][1] = *(const short8*)&Pl[w][l15 * 72 + 32 + quad * 8];
    }
    if (act0) {            // act0 implies act1: both groups active
      __builtin_amdgcn_s_setprio(1);
      for (int c = 0; c < 2; c++) {
        for (int jd = 0; jd < 8; jd++) {
          int row = jd * 16 + l15;
          short8 vf = *(const short8*)&VtB[row * 64 + (((c * 4 + quad) ^ (row & 7))) * 8];
          o[0][jd] = __builtin_amdgcn_mfma_f32_16x16x32_bf16(pf[0][c], vf, o[0][jd], 0, 0, 0);
          o[1][jd] = __builtin_amdgcn_mfma_f32_16x16x32_bf16(pf[1][c], vf, o[1][jd], 0, 0, 0);
        }
      }
      __builtin_amdgcn_s_setprio(0);
    } else if (act1) {     // tail: only the upper 16-query group remains causal-active
      for (int c = 0; c < 2; c++) {
        for (int jd = 0; jd < 8; jd++) {
          int row = jd * 16 + l15;
          short8 vf = *(const short8*)&VtB[row * 64 + (((c * 4 + quad) ^ (row & 7))) * 8];
          o[1][jd] = __builtin_amdgcn_mfma_f32_16x16x32_bf16(pf[1][c], vf, o[1][jd], 0, 0, 0);
        }
      }
    }
  }

  for (int g = 0; g < 2; g++) {
    float l = lrun[g];
    l += __shfl_xor(l, 16, 64);
    l += __shfl_xor(l, 32, 64);
    if (lane < 16) abuf[w][g][lane] = 1.0f / l;
  }
  for (int g = 0; g < 2; g++) {
    f32x4 lv = *(const f32x4*)&abuf[w][g][quad * 4];
    for (int r = 0; r < 4; r++) {
      int qrow = wq0 + g * 16 + quad * 4 + r;
      unsigned short* op = attnOut + (long)qrow * DMODEL + h * HD;
      for (int jd = 0; jd < 8; jd++) op[jd * 16 + l15] = f2bf(o[g][jd][r] * lv[r]);
    }
  }
}

// ---------------- launcher ----------------
extern "C" void kernel_launch(void* const* d_in, const int* in_sizes, int n_in,
                              void* d_out, int out_size, void* d_ws, size_t ws_size,
                              hipStream_t stream) {
  (void)in_sizes; (void)n_in; (void)out_size; (void)ws_size;
  const float* hidden    = (const float*)d_in[0];
  const float* sink_k    = (const float*)d_in[1];
  const float* sink_v    = (const float*)d_in[2];
  const float* win_k     = (const float*)d_in[3];
  const float* win_v     = (const float*)d_in[4];
  const int*   sink_pos  = (const int*)d_in[5];
  const int*   key_pos   = (const int*)d_in[6];
  const float* sink_mask = (const float*)d_in[7];
  const float* key_mask  = (const float*)d_in[8];
  const float* Wq = (const float*)d_in[9];
  const float* Wk = (const float*)d_in[10];
  const float* Wv = (const float*)d_in[11];
  const float* Wo = (const float*)d_in[12];
  float* out = (float*)d_out;

  char* ws = (char*)d_ws;
  unsigned short* hidB  = (unsigned short*)(ws + 0);           // 16.8 MB; attn reuses
  unsigned short* attn  = (unsigned short*)(ws + 0);
  unsigned short* WoT   = (unsigned short*)(ws + 16777216L);   // 33.5 MB
  unsigned short* WqkvT = (unsigned short*)(ws + 50331648L);   // 50.3 MB
  unsigned short* Qb    = (unsigned short*)(ws + 100663296L);  // 16.8 MB
  unsigned short* Kb    = (unsigned short*)(ws + 117440512L);  // 8.65 MB
  unsigned short* VTb   = (unsigned short*)(ws + 126091264L);  // 8.65 MB
  float2* postab        = (float2*)(ws + 134742016L);          // 1 MB
  float* bias           = (float*)(ws + 135790592L);           // 16.9 KB
  int* maxp             = (int*)(ws + 135807488L);

  maxpos_kernel<<<1, 256, 0, stream>>>(sink_pos, key_pos, maxp);
  bias_kernel<<<(KT_PAD + 255) / 256, 256, 0, stream>>>(sink_mask, key_mask, bias);
  postab_kernel<<<QLEN, 64, 0, stream>>>(maxp, postab);
  cvt_kernel<<<(QLEN * DMODEL / 4) / 256, 256, 0, stream>>>(hidden, hidB);
  transpose_all<<<dim3(320, 128), dim3(32, 8), 0, stream>>>(Wq, Wk, Wv, Wo, WqkvT, WoT);

  gemm_qkv<<<dim3(48, 16), 256, 0, stream>>>(hidB, WqkvT, postab, Qb, Kb, VTb);

  rope_cache<<<dim3(CUR0, NKV), 128, 0, stream>>>(sink_k, win_k, sink_pos, key_pos, Kb);
  scatter_cache<<<dim3(65, 4, NKV), dim3(32, 8), 0, stream>>>(sink_v, win_v, VTb);
  pad_zero<<<(NKV * (KT_PAD - KTOT) * HD + 255) / 256, 256, 0, stream>>>(Kb, VTb);

  attn_kernel<<<dim3(32, 16), 256, 0, stream>>>(Qb, Kb, VTb, bias, attn);

  gemm_bt<<<dim3(32, 16), 256, 0, stream>>>(attn, WoT, out, QLEN, DMODEL, DMODEL);
}

// Round 2
// 693.641 us; speedup vs baseline: 1.1054x; 1.0889x over previous
//
#include <hip/hip_runtime.h>
#include <hip/hip_bf16.h>

typedef __attribute__((ext_vector_type(8))) short short8;
typedef __attribute__((ext_vector_type(4))) float f32x4;
typedef __attribute__((ext_vector_type(4))) unsigned short us4;

#define DEV static __device__ __forceinline__

constexpr int QLEN = 2048;
constexpr int DMODEL = 4096;
constexpr int NHEAD = 32;
constexpr int NKV = 8;
constexpr int HD = 128;
constexpr int NSINK = 4;
constexpr int NWIN = 2048;
constexpr int CUR0 = NSINK + NWIN;     // 2052
constexpr int KTOT = CUR0 + QLEN;      // 4100
constexpr int KT_PAD = 4224;           // 66 * 64
constexpr float LOG2E = 1.4426950408889634f;
constexpr float NEGBIG = -1.0e30f;
constexpr float MSHIFT = 32.0f;        // fixed softmax shift (log2 units)
constexpr float QSCALE = 0.08838834764831843f * LOG2E; // 1/sqrt(128) * log2(e)

DEV unsigned short f2bf(float f) {
  unsigned int u = __float_as_uint(f);
  u += 0x7fffu + ((u >> 16) & 1u);
  return (unsigned short)(u >> 16);
}

DEV unsigned int pk2(float a, float b) {   // packed bf16 pair, RNE (v_cvt_pk_bf16_f32)
  __hip_bfloat162 h = __float22bfloat162_rn(make_float2(a, b));
  return *(unsigned int*)&h;
}

DEV void gld16(const void* g, void* l) {
  __builtin_amdgcn_global_load_lds((const __attribute__((address_space(1))) void*)g,
                                   (__attribute__((address_space(3))) void*)l, 16, 0, 0);
}

// ---------------- small prep kernels ----------------

__global__ void maxpos_kernel(const int* __restrict__ sp, const int* __restrict__ kp,
                              int* __restrict__ outp) {
  __shared__ int red[256];
  int t = threadIdx.x;
  int m = -0x7fffffff;
  for (int i = t; i < NSINK; i += 256) m = max(m, sp[i]);
  for (int i = t; i < NWIN; i += 256) m = max(m, kp[i]);
  red[t] = m;
  __syncthreads();
  for (int s = 128; s > 0; s >>= 1) {
    if (t < s) red[t] = max(red[t], red[t + s]);
    __syncthreads();
  }
  if (t == 0) outp[0] = red[0] + 1;
}

__global__ void bias_kernel(const float* __restrict__ sm, const float* __restrict__ km,
                            float* __restrict__ bias) {
  int kk = blockIdx.x * 256 + threadIdx.x;
  if (kk >= KT_PAD) return;
  float b;
  if (kk < NSINK) b = sm[kk] * NEGBIG * LOG2E - MSHIFT;
  else if (kk < CUR0) b = km[kk - NSINK] * NEGBIG * LOG2E - MSHIFT;
  else if (kk < KTOT) b = -MSHIFT;
  else b = NEGBIG;
  bias[kk] = b;
}

// cos/sin table for query positions: tab[q][j] = (cos,sin)((maxp+q) * invf(j))
__global__ void postab_kernel(const int* __restrict__ maxp, float2* __restrict__ tab) {
  int q = blockIdx.x, j = threadIdx.x;
  float pos = (float)(maxp[0] + q);
  float invf = exp2f(-(float)(2 * j) * (13.287712379549449f / 128.0f));
  float ang = pos * invf;
  tab[q * 64 + j] = make_float2(__cosf(ang), __sinf(ang));
}

__global__ __launch_bounds__(256) void cvt_kernel(const float* __restrict__ src,
                                                  unsigned short* __restrict__ dst) {
  long i = ((long)blockIdx.x * 256 + threadIdx.x) * 4;
  f32x4 v = *(const f32x4*)(src + i);
  us4 o;
  o[0] = f2bf(v[0]); o[1] = f2bf(v[1]); o[2] = f2bf(v[2]); o[3] = f2bf(v[3]);
  *(us4*)(dst + i) = o;
}

// all 4 weight transposes in one launch. x: [0,128)=Wq [128,160)=Wk [160,192)=Wv [192,320)=Wo
__global__ void transpose_all(const float* __restrict__ Wq, const float* __restrict__ Wk,
                              const float* __restrict__ Wv, const float* __restrict__ Wo,
                              unsigned short* __restrict__ WqkvT,
                              unsigned short* __restrict__ WoT) {
  __shared__ float t[32][33];
  int bx = blockIdx.x;
  const float* W; unsigned short* WT; int N; int xl;
  if (bx < 128)      { W = Wq; WT = WqkvT;                   N = 4096; xl = bx; }
  else if (bx < 160) { W = Wk; WT = WqkvT + 4096L * 4096;    N = 1024; xl = bx - 128; }
  else if (bx < 192) { W = Wv; WT = WqkvT + 5120L * 4096;    N = 1024; xl = bx - 160; }
  else               { W = Wo; WT = WoT;                     N = 4096; xl = bx - 192; }
  int n0 = xl * 32, k0 = blockIdx.y * 32;
  int tx = threadIdx.x, ty = threadIdx.y;
  for (int p = 0; p < 4; p++) {
    int k = k0 + ty + p * 8;
    t[ty + p * 8][tx] = W[(long)k * N + n0 + tx];
  }
  __syncthreads();
  for (int p = 0; p < 4; p++) {
    int n = n0 + ty + p * 8;
    WT[(long)n * 4096 + k0 + tx] = f2bf(t[tx][ty + p * 8]);
  }
}

// ---------------- generic GEMM (used for output projection, f32 C) ----------------
__global__ __launch_bounds__(256) void gemm_bt(const unsigned short* __restrict__ A,
                                               const unsigned short* __restrict__ Bt,
                                               float* __restrict__ C,
                                               int M, int N, int K) {
  __shared__ __align__(16) unsigned short As[128 * 64];
  __shared__ __align__(16) unsigned short Bs[128 * 64];
  int tid = threadIdx.x, lane = tid & 63, w = tid >> 6;
  int m0 = blockIdx.y * 128, n0 = blockIdx.x * 128;
  int wm = w & 1, wn = w >> 1;
  f32x4 z = {0.f, 0.f, 0.f, 0.f};
  f32x4 acc[4][4];
  for (int i = 0; i < 4; i++) for (int j = 0; j < 4; j++) acc[i][j] = z;
  int nK = K >> 6;
  for (int ks = 0; ks < nK; ks++) {
    long k0 = (long)ks << 6;
    for (int t = 0; t < 4; t++) {
      int chunk = w * 4 + t;
      int row = chunk * 8 + (lane >> 3);
      int kbs = (lane & 7) ^ (row & 7);
      gld16(A + ((long)(m0 + row) * K + k0 + kbs * 8), &As[chunk * 512 + lane * 8]);
      gld16(Bt + ((long)(n0 + row) * K + k0 + kbs * 8), &Bs[chunk * 512 + lane * 8]);
    }
    __syncthreads();
    for (int kc = 0; kc < 2; kc++) {
      short8 af[4], bf[4];
      int c = kc * 4 + (lane >> 4);
      for (int i = 0; i < 4; i++) {
        int ra = wm * 64 + i * 16 + (lane & 15);
        af[i] = *(const short8*)&As[ra * 64 + (c ^ (ra & 7)) * 8];
        int rb = wn * 64 + i * 16 + (lane & 15);
        bf[i] = *(const short8*)&Bs[rb * 64 + (c ^ (rb & 7)) * 8];
      }
      for (int i = 0; i < 4; i++)
        for (int j = 0; j < 4; j++)
          acc[i][j] = __builtin_amdgcn_mfma_f32_16x16x32_bf16(af[i], bf[j], acc[i][j], 0, 0, 0);
    }
    __syncthreads();
  }
  for (int i = 0; i < 4; i++) {
    int m = m0 + wm * 64 + i * 16 + ((lane >> 4) << 2);
    for (int j = 0; j < 4; j++) {
      int n = n0 + wn * 64 + j * 16 + (lane & 15);
      float* cp = C + (long)m * N + n;
      for (int r = 0; r < 4; r++) cp[(long)r * N] = acc[i][j][r];
    }
  }
}

// ---------------- fused QKV GEMM + RoPE + scatter epilogue ----------------
// A=[2048][4096] bf16, Bt=[6144][4096] bf16. C-tile 128x128 aligns with heads:
// nb<32 -> Q head nb (rope, *QSCALE -> Qb); nb in[32,40) -> K-cur kvh nb-32
// (rope -> Kb at CUR0+); nb>=40 -> V kvh nb-40 (transpose -> VTb at CUR0+).
__global__ __launch_bounds__(256) void gemm_qkv(const unsigned short* __restrict__ A,
                                                const unsigned short* __restrict__ Bt,
                                                const float2* __restrict__ postab,
                                                unsigned short* __restrict__ Qb,
                                                unsigned short* __restrict__ Kb,
                                                unsigned short* __restrict__ VTb) {
  __shared__ __align__(16) char smem[66 * 512];           // 33 KB: staging / epilogue union
  unsigned short* As = (unsigned short*)smem;             // 16 KB
  unsigned short* Bs = As + 8192;                         // 16 KB
  float* Cs = (float*)smem;                               // 64 x 129 f32 = 33024 B
  constexpr int K = 4096;
  int tid = threadIdx.x, lane = tid & 63, w = tid >> 6;
  int quad = lane >> 4, l15 = lane & 15;
  int m0 = blockIdx.y * 128, n0 = blockIdx.x * 128;
  int wm = w & 1, wn = w >> 1;
  f32x4 z = {0.f, 0.f, 0.f, 0.f};
  f32x4 acc[4][4];
  for (int i = 0; i < 4; i++) for (int j = 0; j < 4; j++) acc[i][j] = z;
  for (int ks = 0; ks < K / 64; ks++) {
    long k0 = (long)ks << 6;
    for (int t = 0; t < 4; t++) {
      int chunk = w * 4 + t;
      int row = chunk * 8 + (lane >> 3);
      int kbs = (lane & 7) ^ (row & 7);
      gld16(A + ((long)(m0 + row) * K + k0 + kbs * 8), &As[chunk * 512 + lane * 8]);
      gld16(Bt + ((long)(n0 + row) * K + k0 + kbs * 8), &Bs[chunk * 512 + lane * 8]);
    }
    __syncthreads();
    for (int kc = 0; kc < 2; kc++) {
      short8 af[4], bf[4];
      int c = kc * 4 + quad;
      for (int i = 0; i < 4; i++) {
        int ra = wm * 64 + i * 16 + l15;
        af[i] = *(const short8*)&As[ra * 64 + (c ^ (ra & 7)) * 8];
        int rb = wn * 64 + i * 16 + l15;
        bf[i] = *(const short8*)&Bs[rb * 64 + (c ^ (rb & 7)) * 8];
      }
      for (int i = 0; i < 4; i++)
        for (int j = 0; j < 4; j++)
          acc[i][j] = __builtin_amdgcn_mfma_f32_16x16x32_bf16(af[i], bf[j], acc[i][j], 0, 0, 0);
    }
    __syncthreads();
  }

  int nb = blockIdx.x;
  int part = (nb < 32) ? 0 : (nb < 40 ? 1 : 2);
  int hh = (part == 0) ? nb : (part == 1 ? nb - 32 : nb - 40);
  float scale = (part == 0) ? QSCALE : 1.0f;

  for (int pass = 0; pass < 2; pass++) {
    __syncthreads();
    if (wm == pass) {
      for (int i = 0; i < 4; i++)
        for (int j = 0; j < 4; j++)
          for (int r = 0; r < 4; r++)
            Cs[(i * 16 + quad * 4 + r) * 129 + wn * 64 + j * 16 + l15] = acc[i][j][r];
    }
    __syncthreads();
    if (part < 2) {
      if (tid < 128) {
        int r = tid & 63, hf = tid >> 6;
        int query = m0 + pass * 64 + r;
        const float2* tb = postab + query * 64;
        unsigned short* dst = (part == 0)
            ? Qb + ((long)hh * QLEN + query) * HD + hf * 64
            : Kb + ((long)hh * KT_PAD + CUR0 + query) * HD + hf * 64;
        for (int j = 0; j < 64; j += 4) {
          float v[4];
          for (int u = 0; u < 4; u++) {
            float2 cs = tb[j + u];
            int d = hf * 64 + j + u;
            float xa = Cs[r * 129 + d];
            float xb = Cs[r * 129 + (d ^ 64)];
            v[u] = (xa * cs.x + (hf ? xb : -xb) * cs.y) * scale;
          }
          uint2 o4;
          o4.x = pk2(v[0], v[1]);
          o4.y = pk2(v[2], v[3]);
          *(uint2*)(dst + j) = o4;
        }
      }
    } else {
      if (tid < 128) {
        int d = tid;
        unsigned short* dst = VTb + ((long)hh * HD + d) * KT_PAD + CUR0 + m0 + pass * 64;
        for (int m = 0; m < 64; m += 4) {
          uint2 o4;
          o4.x = pk2(Cs[m * 129 + d], Cs[(m + 1) * 129 + d]);
          o4.y = pk2(Cs[(m + 2) * 129 + d], Cs[(m + 3) * 129 + d]);
          *(uint2*)(dst + m) = o4;
        }
      }
    }
  }
}

// ---------------- cache (sink + window) RoPE / V scatter ----------------
__global__ void rope_cache(const float* __restrict__ sink_k, const float* __restrict__ win_k,
                           const int* __restrict__ sp, const int* __restrict__ kp,
                           unsigned short* __restrict__ Kb) {
  int s = blockIdx.x, kvh = blockIdx.y, d = threadIdx.x;
  const float* src; int pos;
  if (s < NSINK) { src = sink_k + ((long)kvh * NSINK + s) * HD; pos = sp[s]; }
  else           { src = win_k + ((long)kvh * NWIN + (s - NSINK)) * HD; pos = kp[s - NSINK]; }
  float x = src[d];
  float x2 = src[d ^ 64];
  float rot = (d < 64) ? -x2 : x2;
  int i = d & 63;
  float invf = exp2f(-(float)(2 * i) * (13.287712379549449f / 128.0f));
  float ang = (float)pos * invf;
  float c = __cosf(ang), sn = __sinf(ang);
  Kb[((long)kvh * KT_PAD + s) * HD + d] = f2bf(x * c + rot * sn);
}

// x<64: window chunk; x==64: sinks
__global__ void scatter_cache(const float* __restrict__ sink_v, const float* __restrict__ win_v,
                              unsigned short* __restrict__ VTb) {
  __shared__ float t[32][33];
  int kvh = blockIdx.z, d0 = blockIdx.y * 32;
  const float* src; int S, s0, dstPos0;
  if (blockIdx.x < 64) { src = win_v + (long)kvh * NWIN * HD; S = NWIN; s0 = blockIdx.x * 32; dstPos0 = NSINK; }
  else                 { src = sink_v + (long)kvh * NSINK * HD; S = NSINK; s0 = 0; dstPos0 = 0; }
  int tx = threadIdx.x, ty = threadIdx.y;
  for (int p = 0; p < 4; p++) {
    int s = s0 + ty + p * 8;
    if (s < S) t[ty + p * 8][tx] = src[(long)s * HD + d0 + tx];
  }
  __syncthreads();
  for (int p = 0; p < 4; p++) {
    int d = d0 + ty + p * 8;
    int s = s0 + tx;
    if (s < S)
      VTb[((long)kvh * HD + d) * KT_PAD + dstPos0 + s] = f2bf(t[tx][ty + p * 8]);
  }
}

__global__ void pad_zero(unsigned short* __restrict__ Kb, unsigned short* __restrict__ VTb) {
  int idx = blockIdx.x * 256 + threadIdx.x;
  int total = NKV * (KT_PAD - KTOT) * HD;
  if (idx >= total) return;
  int per = (KT_PAD - KTOT) * HD;
  int kvh = idx / per;
  int rem = idx % per;
  int pos = KTOT + rem / HD;
  int d = rem % HD;
  Kb[((long)kvh * KT_PAD + pos) * HD + d] = 0;
  VTb[((long)kvh * HD + d) * KT_PAD + pos] = 0;
}

// ---------------- flash attention (8 waves, 16q/wave, S^T, fixed-shift softmax) ----
// 8-wave staging: 16 chunks of 1KB each for K (64x128) and V^T (128x64).
DEV void stage_kv(const unsigned short* __restrict__ Kbase,
                  const unsigned short* __restrict__ Vbase, long k0,
                  unsigned short* KtB, unsigned short* VtB, int w, int lane) {
  int quad = lane >> 4, l15 = lane & 15;
  for (int t = 0; t < 2; t++) {
    int chunk = w * 2 + t;                 // 0..15
    { int row = chunk * 4 + quad;          // 0..63
      int kbs = l15 ^ (row & 15);
      gld16(Kbase + (k0 + row) * HD + kbs * 8, &KtB[chunk * 512 + lane * 8]); }
    { int row = chunk * 8 + (lane >> 3);   // 0..127
      int kbs = (lane & 7) ^ (row & 7);
      gld16(Vbase + (long)row * KT_PAD + k0 + kbs * 8, &VtB[chunk * 512 + lane * 8]); }
  }
}

__global__ __launch_bounds__(512, 4) void attn_kernel(
    const unsigned short* __restrict__ Qb,
    const unsigned short* __restrict__ Kb,
    const unsigned short* __restrict__ VTb,
    const float* __restrict__ biasArr,
    unsigned short* __restrict__ attnOut) {
  // LDS = 32K (Kt) + 32K (Vt) + 16K (Pl) = 81920 B exactly -> 2 blocks/CU.
  __shared__ __align__(16) unsigned short Kt[2][64 * 128];
  __shared__ __align__(16) unsigned short Vt[2][128 * 64];
  __shared__ __align__(16) unsigned short Pl[8][1024];  // per-wave 16q x 64k bf16, XOR-swizzled
  int tid = threadIdx.x, lane = tid & 63, w = tid >> 6;
  int quad = lane >> 4, l15 = lane & 15;
  int hh = blockIdx.x;
  int h = (hh & 7) * 4 + (hh >> 3);
  int kvh = hh & 7;
  int yt = blockIdx.y;
  int qt = (yt < 8) ? yt : (23 - yt);
  int q0 = qt * 128;
  int wq0 = q0 + w * 16;                  // this wave's 16 queries

  short8 qf[4];
  for (int kc = 0; kc < 4; kc++) {
    long off = ((long)h * QLEN + wq0 + l15) * HD + kc * 32 + quad * 8;
    qf[kc] = *(const short8*)(Qb + off);
  }
  short8 ones;
  for (int i = 0; i < 8; i++) ones[i] = (short)0x3F80;  // bf16 1.0

  f32x4 z = {0.f, 0.f, 0.f, 0.f};
  f32x4 o[8];
  for (int j = 0; j < 8; j++) o[j] = z;
  f32x4 lacc = z;                          // softmax denominator via ones-MFMA

  int nsteps = min(KT_PAD / 64, (CUR0 + q0 + 127) / 64 + 1);
  const unsigned short* Kbase = Kb + (long)kvh * KT_PAD * HD;
  const unsigned short* Vbase = VTb + (long)kvh * HD * KT_PAD;

  stage_kv(Kbase, Vbase, 0, Kt[0], Vt[0], w, lane);

  char* PlW = (char*)&Pl[w][0];
  int pwbase = l15 * 128;                  // row byte base (row = query lane)
  int pxor = (l15 & 7) << 4;               // bank swizzle, bits 4-6

  for (int st = 0; st < nsteps; st++) {
    long k0 = (long)st * 64;
    int cur = st & 1;
    __syncthreads();

    f32x4 b4[4];
    for (int t = 0; t < 4; t++)
      b4[t] = *(const f32x4*)&biasArr[k0 + 16 * t + quad * 4];

    if (st + 1 < nsteps)
      stage_kv(Kbase, Vbase, k0 + 64, Kt[cur ^ 1], Vt[cur ^ 1], w, lane);

    const unsigned short* KtB = Kt[cur];
    const unsigned short* VtB = Vt[cur];

    f32x4 stt[4];
    for (int t = 0; t < 4; t++) stt[t] = z;
    __builtin_amdgcn_s_setprio(1);
    for (int kc = 0; kc < 4; kc++) {
      for (int t = 0; t < 4; t++) {
        int row = 16 * t + l15;
        short8 kf = *(const short8*)&KtB[row * 128 + (((kc * 4 + quad) ^ (row & 15))) * 8];
        stt[t] = __builtin_amdgcn_mfma_f32_16x16x32_bf16(kf, qf[kc], stt[t], 0, 0, 0);
      }
    }
    __builtin_amdgcn_s_setprio(0);

    if ((int)k0 <= wq0 + 15 + CUR0) {
      int query = wq0 + l15;
      bool needMask = (int)k0 + 63 > wq0 + CUR0;
      if (needMask) {
        for (int t = 0; t < 4; t++) {
          float p[4];
          for (int r = 0; r < 4; r++) {
            int key = (int)k0 + 16 * t + quad * 4 + r;
            float v = stt[t][r] + b4[t][r];
            if (key > query + CUR0) v = NEGBIG;
            p[r] = exp2f(v);
          }
          uint2 pw;
          pw.x = pk2(p[0], p[1]);
          pw.y = pk2(p[2], p[3]);
          *(uint2*)(PlW + (pwbase + ((32 * t + 8 * quad) ^ pxor))) = pw;
        }
      } else {
        for (int t = 0; t < 4; t++) {
          float p[4];
          for (int r = 0; r < 4; r++) p[r] = exp2f(stt[t][r] + b4[t][r]);
          uint2 pw;
          pw.x = pk2(p[0], p[1]);
          pw.y = pk2(p[2], p[3]);
          *(uint2*)(PlW + (pwbase + ((32 * t + 8 * quad) ^ pxor))) = pw;
        }
      }
      short8 pf[2];
      pf[0] = *(const short8*)(PlW + (pwbase + ((16 * quad) ^ pxor)));
      pf[1] = *(const short8*)(PlW + (pwbase + ((64 + 16 * quad) ^ pxor)));
      __builtin_amdgcn_s_setprio(1);
      for (int c = 0; c < 2; c++) {
        lacc = __builtin_amdgcn_mfma_f32_16x16x32_bf16(pf[c], ones, lacc, 0, 0, 0);
        for (int jd = 0; jd < 8; jd++) {
          int row = jd * 16 + l15;
          short8 vf = *(const short8*)&VtB[row * 64 + (((c * 4 + quad) ^ (row & 7))) * 8];
          o[jd] = __builtin_amdgcn_mfma_f32_16x16x32_bf16(pf[c], vf, o[jd], 0, 0, 0);
        }
      }
      __builtin_amdgcn_s_setprio(0);
    }
  }

  // lacc[r] = sum_k P[query = wq0+quad*4+r][k]  (same layout as o rows)
  f32x4 linv;
  for (int r = 0; r < 4; r++) linv[r] = 1.0f / lacc[r];
  for (int r = 0; r < 4; r++) {
    int qrow = wq0 + quad * 4 + r;
    unsigned short* op = attnOut + (long)qrow * DMODEL + h * HD;
    for (int jd = 0; jd < 8; jd++) op[jd * 16 + l15] = f2bf(o[jd][r] * linv[r]);
  }
}

// ---------------- launcher ----------------
extern "C" void kernel_launch(void* const* d_in, const int* in_sizes, int n_in,
                              void* d_out, int out_size, void* d_ws, size_t ws_size,
                              hipStream_t stream) {
  (void)in_sizes; (void)n_in; (void)out_size; (void)ws_size;
  const float* hidden    = (const float*)d_in[0];
  const float* sink_k    = (const float*)d_in[1];
  const float* sink_v    = (const float*)d_in[2];
  const float* win_k     = (const float*)d_in[3];
  const float* win_v     = (const float*)d_in[4];
  const int*   sink_pos  = (const int*)d_in[5];
  const int*   key_pos   = (const int*)d_in[6];
  const float* sink_mask = (const float*)d_in[7];
  const float* key_mask  = (const float*)d_in[8];
  const float* Wq = (const float*)d_in[9];
  const float* Wk = (const float*)d_in[10];
  const float* Wv = (const float*)d_in[11];
  const float* Wo = (const float*)d_in[12];
  float* out = (float*)d_out;

  char* ws = (char*)d_ws;
  unsigned short* hidB  = (unsigned short*)(ws + 0);           // 16.8 MB; attn reuses
  unsigned short* attn  = (unsigned short*)(ws + 0);
  unsigned short* WoT   = (unsigned short*)(ws + 16777216L);   // 33.5 MB
  unsigned short* WqkvT = (unsigned short*)(ws + 50331648L);   // 50.3 MB
  unsigned short* Qb    = (unsigned short*)(ws + 100663296L);  // 16.8 MB
  unsigned short* Kb    = (unsigned short*)(ws + 117440512L);  // 8.65 MB
  unsigned short* VTb   = (unsigned short*)(ws + 126091264L);  // 8.65 MB
  float2* postab        = (float2*)(ws + 134742016L);          // 1 MB
  float* bias           = (float*)(ws + 135790592L);           // 16.9 KB
  int* maxp             = (int*)(ws + 135807488L);

  maxpos_kernel<<<1, 256, 0, stream>>>(sink_pos, key_pos, maxp);
  bias_kernel<<<(KT_PAD + 255) / 256, 256, 0, stream>>>(sink_mask, key_mask, bias);
  postab_kernel<<<QLEN, 64, 0, stream>>>(maxp, postab);
  cvt_kernel<<<(QLEN * DMODEL / 4) / 256, 256, 0, stream>>>(hidden, hidB);
  transpose_all<<<dim3(320, 128), dim3(32, 8), 0, stream>>>(Wq, Wk, Wv, Wo, WqkvT, WoT);

  gemm_qkv<<<dim3(48, 16), 256, 0, stream>>>(hidB, WqkvT, postab, Qb, Kb, VTb);

  rope_cache<<<dim3(CUR0, NKV), 128, 0, stream>>>(sink_k, win_k, sink_pos, key_pos, Kb);
  scatter_cache<<<dim3(65, 4, NKV), dim3(32, 8), 0, stream>>>(sink_v, win_v, VTb);
  pad_zero<<<(NKV * (KT_PAD - KTOT) * HD + 255) / 256, 256, 0, stream>>>(Kb, VTb);

  attn_kernel<<<dim3(32, 16), 512, 0, stream>>>(Qb, Kb, VTb, bias, attn);

  gemm_bt<<<dim3(32, 16), 256, 0, stream>>>(attn, WoT, out, QLEN, DMODEL, DMODEL);
}

// Round 3
// 619.337 us; speedup vs baseline: 1.2380x; 1.1200x over previous
//
#include <hip/hip_runtime.h>
#include <hip/hip_bf16.h>

typedef __attribute__((ext_vector_type(8))) short short8;
typedef __attribute__((ext_vector_type(4))) float f32x4;
typedef __attribute__((ext_vector_type(4))) unsigned short us4;

#define DEV static __device__ __forceinline__

constexpr int QLEN = 2048;
constexpr int DMODEL = 4096;
constexpr int NHEAD = 32;
constexpr int NKV = 8;
constexpr int HD = 128;
constexpr int NSINK = 4;
constexpr int NWIN = 2048;
constexpr int CUR0 = NSINK + NWIN;     // 2052
constexpr int KTOT = CUR0 + QLEN;      // 4100
constexpr int KT_PAD = 4224;           // 66 * 64
constexpr float LOG2E = 1.4426950408889634f;
constexpr float NEGBIG = -1.0e30f;
constexpr float MSHIFT = 32.0f;        // fixed softmax shift (log2 units)
constexpr float QSCALE = 0.08838834764831843f * LOG2E; // 1/sqrt(128) * log2(e)

DEV unsigned short f2bf(float f) {
  unsigned int u = __float_as_uint(f);
  u += 0x7fffu + ((u >> 16) & 1u);
  return (unsigned short)(u >> 16);
}

DEV unsigned int pk2(float a, float b) {   // packed bf16 pair, RNE (v_cvt_pk_bf16_f32)
  __hip_bfloat162 h = __float22bfloat162_rn(make_float2(a, b));
  return *(unsigned int*)&h;
}

DEV void gld16(const void* g, void* l) {
  __builtin_amdgcn_global_load_lds((const __attribute__((address_space(1))) void*)g,
                                   (__attribute__((address_space(3))) void*)l, 16, 0, 0);
}

// ---------------- small prep kernels ----------------

__global__ void maxpos_kernel(const int* __restrict__ sp, const int* __restrict__ kp,
                              int* __restrict__ outp) {
  __shared__ int red[256];
  int t = threadIdx.x;
  int m = -0x7fffffff;
  for (int i = t; i < NSINK; i += 256) m = max(m, sp[i]);
  for (int i = t; i < NWIN; i += 256) m = max(m, kp[i]);
  red[t] = m;
  __syncthreads();
  for (int s = 128; s > 0; s >>= 1) {
    if (t < s) red[t] = max(red[t], red[t + s]);
    __syncthreads();
  }
  if (t == 0) outp[0] = red[0] + 1;
}

__global__ void bias_kernel(const float* __restrict__ sm, const float* __restrict__ km,
                            float* __restrict__ bias) {
  int kk = blockIdx.x * 256 + threadIdx.x;
  if (kk >= KT_PAD) return;
  float b;
  if (kk < NSINK) b = sm[kk] * NEGBIG * LOG2E - MSHIFT;
  else if (kk < CUR0) b = km[kk - NSINK] * NEGBIG * LOG2E - MSHIFT;
  else if (kk < KTOT) b = -MSHIFT;
  else b = NEGBIG;
  bias[kk] = b;
}

// cos/sin table for query positions: tab[q][j] = (cos,sin)((maxp+q) * invf(j))
__global__ void postab_kernel(const int* __restrict__ maxp, float2* __restrict__ tab) {
  int q = blockIdx.x, j = threadIdx.x;
  float pos = (float)(maxp[0] + q);
  float invf = exp2f(-(float)(2 * j) * (13.287712379549449f / 128.0f));
  float ang = pos * invf;
  tab[q * 64 + j] = make_float2(__cosf(ang), __sinf(ang));
}

__global__ __launch_bounds__(256) void cvt_kernel(const float* __restrict__ src,
                                                  unsigned short* __restrict__ dst) {
  long i = ((long)blockIdx.x * 256 + threadIdx.x) * 4;
  f32x4 v = *(const f32x4*)(src + i);
  us4 o;
  o[0] = f2bf(v[0]); o[1] = f2bf(v[1]); o[2] = f2bf(v[2]); o[3] = f2bf(v[3]);
  *(us4*)(dst + i) = o;
}

// all 4 weight transposes in one launch. x: [0,128)=Wq [128,160)=Wk [160,192)=Wv [192,320)=Wo
__global__ void transpose_all(const float* __restrict__ Wq, const float* __restrict__ Wk,
                              const float* __restrict__ Wv, const float* __restrict__ Wo,
                              unsigned short* __restrict__ WqkvT,
                              unsigned short* __restrict__ WoT) {
  __shared__ float t[32][33];
  int bx = blockIdx.x;
  const float* W; unsigned short* WT; int N; int xl;
  if (bx < 128)      { W = Wq; WT = WqkvT;                   N = 4096; xl = bx; }
  else if (bx < 160) { W = Wk; WT = WqkvT + 4096L * 4096;    N = 1024; xl = bx - 128; }
  else if (bx < 192) { W = Wv; WT = WqkvT + 5120L * 4096;    N = 1024; xl = bx - 160; }
  else               { W = Wo; WT = WoT;                     N = 4096; xl = bx - 192; }
  int n0 = xl * 32, k0 = blockIdx.y * 32;
  int tx = threadIdx.x, ty = threadIdx.y;
  for (int p = 0; p < 4; p++) {
    int k = k0 + ty + p * 8;
    t[ty + p * 8][tx] = W[(long)k * N + n0 + tx];
  }
  __syncthreads();
  for (int p = 0; p < 4; p++) {
    int n = n0 + ty + p * 8;
    WT[(long)n * 4096 + k0 + tx] = f2bf(t[tx][ty + p * 8]);
  }
}

// ---------------- generic GEMM (used for output projection, f32 C) ----------------
// Grid MUST be dim3(nx, 16) with nwg % 8 == 0. M-fastest XCD-chunked remap:
// consecutive tile ids within one XCD chunk share the Bt panel (L2-resident).
__global__ __launch_bounds__(256) void gemm_bt(const unsigned short* __restrict__ A,
                                               const unsigned short* __restrict__ Bt,
                                               float* __restrict__ C,
                                               int M, int N, int K) {
  __shared__ __align__(16) unsigned short As[128 * 64];
  __shared__ __align__(16) unsigned short Bs[128 * 64];
  int tid = threadIdx.x, lane = tid & 63, w = tid >> 6;
  int nwg = gridDim.x * gridDim.y;
  int orig = blockIdx.y * gridDim.x + blockIdx.x;
  int wg = (orig & 7) * (nwg >> 3) + (orig >> 3);   // XCD-chunked (nwg%8==0)
  int mx = wg & 15, nx = wg >> 4;                   // gridDim.y == 16, M fastest
  int m0 = mx * 128, n0 = nx * 128;
  int wm = w & 1, wn = w >> 1;
  f32x4 z = {0.f, 0.f, 0.f, 0.f};
  f32x4 acc[4][4];
  for (int i = 0; i < 4; i++) for (int j = 0; j < 4; j++) acc[i][j] = z;
  int nK = K >> 6;
  for (int ks = 0; ks < nK; ks++) {
    long k0 = (long)ks << 6;
    for (int t = 0; t < 4; t++) {
      int chunk = w * 4 + t;
      int row = chunk * 8 + (lane >> 3);
      int kbs = (lane & 7) ^ (row & 7);
      gld16(A + ((long)(m0 + row) * K + k0 + kbs * 8), &As[chunk * 512 + lane * 8]);
      gld16(Bt + ((long)(n0 + row) * K + k0 + kbs * 8), &Bs[chunk * 512 + lane * 8]);
    }
    __syncthreads();
    for (int kc = 0; kc < 2; kc++) {
      short8 af[4], bf[4];
      int c = kc * 4 + (lane >> 4);
      for (int i = 0; i < 4; i++) {
        int ra = wm * 64 + i * 16 + (lane & 15);
        af[i] = *(const short8*)&As[ra * 64 + (c ^ (ra & 7)) * 8];
        int rb = wn * 64 + i * 16 + (lane & 15);
        bf[i] = *(const short8*)&Bs[rb * 64 + (c ^ (rb & 7)) * 8];
      }
      for (int i = 0; i < 4; i++)
        for (int j = 0; j < 4; j++)
          acc[i][j] = __builtin_amdgcn_mfma_f32_16x16x32_bf16(af[i], bf[j], acc[i][j], 0, 0, 0);
    }
    __syncthreads();
  }
  for (int i = 0; i < 4; i++) {
    int m = m0 + wm * 64 + i * 16 + ((lane >> 4) << 2);
    for (int j = 0; j < 4; j++) {
      int n = n0 + wn * 64 + j * 16 + (lane & 15);
      float* cp = C + (long)m * N + n;
      for (int r = 0; r < 4; r++) cp[(long)r * N] = acc[i][j][r];
    }
  }
}

// ---------------- fused QKV GEMM + RoPE + scatter epilogue ----------------
// A=[2048][4096] bf16, Bt=[6144][4096] bf16. C-tile 128x128 aligns with heads:
// nb<32 -> Q head nb (rope, *QSCALE -> Qb); nb in[32,40) -> K-cur kvh nb-32
// (rope -> Kb at CUR0+); nb>=40 -> V kvh nb-40 (transpose -> VTb at CUR0+).
// Grid dim3(48,16); M-fastest XCD-chunked remap as in gemm_bt.
__global__ __launch_bounds__(256) void gemm_qkv(const unsigned short* __restrict__ A,
                                                const unsigned short* __restrict__ Bt,
                                                const float2* __restrict__ postab,
                                                unsigned short* __restrict__ Qb,
                                                unsigned short* __restrict__ Kb,
                                                unsigned short* __restrict__ VTb) {
  __shared__ __align__(16) char smem[66 * 512];           // 33 KB: staging / epilogue union
  unsigned short* As = (unsigned short*)smem;             // 16 KB
  unsigned short* Bs = As + 8192;                         // 16 KB
  float* Cs = (float*)smem;                               // 64 x 129 f32 = 33024 B
  constexpr int K = 4096;
  int tid = threadIdx.x, lane = tid & 63, w = tid >> 6;
  int quad = lane >> 4, l15 = lane & 15;
  int nwg = gridDim.x * gridDim.y;                        // 768
  int orig = blockIdx.y * gridDim.x + blockIdx.x;
  int wg = (orig & 7) * (nwg >> 3) + (orig >> 3);         // XCD-chunked
  int mx = wg & 15, nx = wg >> 4;                         // M fastest
  int m0 = mx * 128, n0 = nx * 128;
  int wm = w & 1, wn = w >> 1;
  f32x4 z = {0.f, 0.f, 0.f, 0.f};
  f32x4 acc[4][4];
  for (int i = 0; i < 4; i++) for (int j = 0; j < 4; j++) acc[i][j] = z;
  for (int ks = 0; ks < K / 64; ks++) {
    long k0 = (long)ks << 6;
    for (int t = 0; t < 4; t++) {
      int chunk = w * 4 + t;
      int row = chunk * 8 + (lane >> 3);
      int kbs = (lane & 7) ^ (row & 7);
      gld16(A + ((long)(m0 + row) * K + k0 + kbs * 8), &As[chunk * 512 + lane * 8]);
      gld16(Bt + ((long)(n0 + row) * K + k0 + kbs * 8), &Bs[chunk * 512 + lane * 8]);
    }
    __syncthreads();
    for (int kc = 0; kc < 2; kc++) {
      short8 af[4], bf[4];
      int c = kc * 4 + quad;
      for (int i = 0; i < 4; i++) {
        int ra = wm * 64 + i * 16 + l15;
        af[i] = *(const short8*)&As[ra * 64 + (c ^ (ra & 7)) * 8];
        int rb = wn * 64 + i * 16 + l15;
        bf[i] = *(const short8*)&Bs[rb * 64 + (c ^ (rb & 7)) * 8];
      }
      for (int i = 0; i < 4; i++)
        for (int j = 0; j < 4; j++)
          acc[i][j] = __builtin_amdgcn_mfma_f32_16x16x32_bf16(af[i], bf[j], acc[i][j], 0, 0, 0);
    }
    __syncthreads();
  }

  int nb = nx;
  int part = (nb < 32) ? 0 : (nb < 40 ? 1 : 2);
  int hh = (part == 0) ? nb : (part == 1 ? nb - 32 : nb - 40);
  float scale = (part == 0) ? QSCALE : 1.0f;

  for (int pass = 0; pass < 2; pass++) {
    __syncthreads();
    if (wm == pass) {
      for (int i = 0; i < 4; i++)
        for (int j = 0; j < 4; j++)
          for (int r = 0; r < 4; r++)
            Cs[(i * 16 + quad * 4 + r) * 129 + wn * 64 + j * 16 + l15] = acc[i][j][r];
    }
    __syncthreads();
    if (part < 2) {
      if (tid < 128) {
        int r = tid & 63, hf = tid >> 6;
        int query = m0 + pass * 64 + r;
        const float2* tb = postab + query * 64;
        unsigned short* dst = (part == 0)
            ? Qb + ((long)hh * QLEN + query) * HD + hf * 64
            : Kb + ((long)hh * KT_PAD + CUR0 + query) * HD + hf * 64;
        for (int j = 0; j < 64; j += 4) {
          float v[4];
          for (int u = 0; u < 4; u++) {
            float2 cs = tb[j + u];
            int d = hf * 64 + j + u;
            float xa = Cs[r * 129 + d];
            float xb = Cs[r * 129 + (d ^ 64)];
            v[u] = (xa * cs.x + (hf ? xb : -xb) * cs.y) * scale;
          }
          uint2 o4;
          o4.x = pk2(v[0], v[1]);
          o4.y = pk2(v[2], v[3]);
          *(uint2*)(dst + j) = o4;
        }
      }
    } else {
      if (tid < 128) {
        int d = tid;
        unsigned short* dst = VTb + ((long)hh * HD + d) * KT_PAD + CUR0 + m0 + pass * 64;
        for (int m = 0; m < 64; m += 4) {
          uint2 o4;
          o4.x = pk2(Cs[m * 129 + d], Cs[(m + 1) * 129 + d]);
          o4.y = pk2(Cs[(m + 2) * 129 + d], Cs[(m + 3) * 129 + d]);
          *(uint2*)(dst + m) = o4;
        }
      }
    }
  }
}

// ---------------- cache (sink + window) RoPE / V scatter ----------------
__global__ void rope_cache(const float* __restrict__ sink_k, const float* __restrict__ win_k,
                           const int* __restrict__ sp, const int* __restrict__ kp,
                           unsigned short* __restrict__ Kb) {
  int s = blockIdx.x, kvh = blockIdx.y, d = threadIdx.x;
  const float* src; int pos;
  if (s < NSINK) { src = sink_k + ((long)kvh * NSINK + s) * HD; pos = sp[s]; }
  else           { src = win_k + ((long)kvh * NWIN + (s - NSINK)) * HD; pos = kp[s - NSINK]; }
  float x = src[d];
  float x2 = src[d ^ 64];
  float rot = (d < 64) ? -x2 : x2;
  int i = d & 63;
  float invf = exp2f(-(float)(2 * i) * (13.287712379549449f / 128.0f));
  float ang = (float)pos * invf;
  float c = __cosf(ang), sn = __sinf(ang);
  Kb[((long)kvh * KT_PAD + s) * HD + d] = f2bf(x * c + rot * sn);
}

// x<64: window chunk; x==64: sinks
__global__ void scatter_cache(const float* __restrict__ sink_v, const float* __restrict__ win_v,
                              unsigned short* __restrict__ VTb) {
  __shared__ float t[32][33];
  int kvh = blockIdx.z, d0 = blockIdx.y * 32;
  const float* src; int S, s0, dstPos0;
  if (blockIdx.x < 64) { src = win_v + (long)kvh * NWIN * HD; S = NWIN; s0 = blockIdx.x * 32; dstPos0 = NSINK; }
  else                 { src = sink_v + (long)kvh * NSINK * HD; S = NSINK; s0 = 0; dstPos0 = 0; }
  int tx = threadIdx.x, ty = threadIdx.y;
  for (int p = 0; p < 4; p++) {
    int s = s0 + ty + p * 8;
    if (s < S) t[ty + p * 8][tx] = src[(long)s * HD + d0 + tx];
  }
  __syncthreads();
  for (int p = 0; p < 4; p++) {
    int d = d0 + ty + p * 8;
    int s = s0 + tx;
    if (s < S)
      VTb[((long)kvh * HD + d) * KT_PAD + dstPos0 + s] = f2bf(t[tx][ty + p * 8]);
  }
}

__global__ void pad_zero(unsigned short* __restrict__ Kb, unsigned short* __restrict__ VTb) {
  int idx = blockIdx.x * 256 + threadIdx.x;
  int total = NKV * (KT_PAD - KTOT) * HD;
  if (idx >= total) return;
  int per = (KT_PAD - KTOT) * HD;
  int kvh = idx / per;
  int rem = idx % per;
  int pos = KTOT + rem / HD;
  int d = rem % HD;
  Kb[((long)kvh * KT_PAD + pos) * HD + d] = 0;
  VTb[((long)kvh * HD + d) * KT_PAD + pos] = 0;
}

// ---------------- flash attention (8 waves, 16q/wave, S^T, fixed-shift softmax) ----
// 8-wave staging: 16 chunks of 1KB each for K (64x128) and V^T (128x64).
DEV void stage_kv(const unsigned short* __restrict__ Kbase,
                  const unsigned short* __restrict__ Vbase, long k0,
                  unsigned short* KtB, unsigned short* VtB, int w, int lane) {
  int quad = lane >> 4, l15 = lane & 15;
  for (int t = 0; t < 2; t++) {
    int chunk = w * 2 + t;                 // 0..15
    { int row = chunk * 4 + quad;          // 0..63
      int kbs = l15 ^ (row & 15);
      gld16(Kbase + (k0 + row) * HD + kbs * 8, &KtB[chunk * 512 + lane * 8]); }
    { int row = chunk * 8 + (lane >> 3);   // 0..127
      int kbs = (lane & 7) ^ (row & 7);
      gld16(Vbase + (long)row * KT_PAD + k0 + kbs * 8, &VtB[chunk * 512 + lane * 8]); }
  }
}

__global__ __launch_bounds__(512, 4) void attn_kernel(
    const unsigned short* __restrict__ Qb,
    const unsigned short* __restrict__ Kb,
    const unsigned short* __restrict__ VTb,
    const float* __restrict__ biasArr,
    unsigned short* __restrict__ attnOut) {
  // LDS = 32K (Kt) + 32K (Vt) + 16K (Pl) = 81920 B exactly -> 2 blocks/CU.
  __shared__ __align__(16) unsigned short Kt[2][64 * 128];
  __shared__ __align__(16) unsigned short Vt[2][128 * 64];
  __shared__ __align__(16) unsigned short Pl[8][1024];  // per-wave 16q x 64k bf16, XOR-swizzled
  int tid = threadIdx.x, lane = tid & 63, w = tid >> 6;
  int quad = lane >> 4, l15 = lane & 15;
  int hh = blockIdx.x;
  int h = (hh & 7) * 4 + (hh >> 3);
  int kvh = hh & 7;
  int yt = blockIdx.y;
  int qt = (yt < 8) ? yt : (23 - yt);
  int q0 = qt * 128;
  int wq0 = q0 + w * 16;                  // this wave's 16 queries

  short8 qf[4];
  for (int kc = 0; kc < 4; kc++) {
    long off = ((long)h * QLEN + wq0 + l15) * HD + kc * 32 + quad * 8;
    qf[kc] = *(const short8*)(Qb + off);
  }
  short8 ones;
  for (int i = 0; i < 8; i++) ones[i] = (short)0x3F80;  // bf16 1.0

  f32x4 z = {0.f, 0.f, 0.f, 0.f};
  f32x4 o[8];
  for (int j = 0; j < 8; j++) o[j] = z;
  f32x4 lacc = z;                          // softmax denominator via ones-MFMA

  int nsteps = min(KT_PAD / 64, (CUR0 + q0 + 127) / 64 + 1);
  const unsigned short* Kbase = Kb + (long)kvh * KT_PAD * HD;
  const unsigned short* Vbase = VTb + (long)kvh * HD * KT_PAD;

  stage_kv(Kbase, Vbase, 0, Kt[0], Vt[0], w, lane);

  char* PlW = (char*)&Pl[w][0];
  int pwbase = l15 * 128;                  // row byte base (row = query lane)
  int pxor = (l15 & 7) << 4;               // bank swizzle, bits 4-6

  for (int st = 0; st < nsteps; st++) {
    long k0 = (long)st * 64;
    int cur = st & 1;
    __syncthreads();

    f32x4 b4[4];
    for (int t = 0; t < 4; t++)
      b4[t] = *(const f32x4*)&biasArr[k0 + 16 * t + quad * 4];

    if (st + 1 < nsteps)
      stage_kv(Kbase, Vbase, k0 + 64, Kt[cur ^ 1], Vt[cur ^ 1], w, lane);

    const unsigned short* KtB = Kt[cur];
    const unsigned short* VtB = Vt[cur];

    f32x4 stt[4];
    for (int t = 0; t < 4; t++) stt[t] = z;
    __builtin_amdgcn_s_setprio(1);
    for (int kc = 0; kc < 4; kc++) {
      for (int t = 0; t < 4; t++) {
        int row = 16 * t + l15;
        short8 kf = *(const short8*)&KtB[row * 128 + (((kc * 4 + quad) ^ (row & 15))) * 8];
        stt[t] = __builtin_amdgcn_mfma_f32_16x16x32_bf16(kf, qf[kc], stt[t], 0, 0, 0);
      }
    }
    __builtin_amdgcn_s_setprio(0);

    if ((int)k0 <= wq0 + 15 + CUR0) {
      int query = wq0 + l15;
      bool needMask = (int)k0 + 63 > wq0 + CUR0;
      if (needMask) {
        for (int t = 0; t < 4; t++) {
          float p[4];
          for (int r = 0; r < 4; r++) {
            int key = (int)k0 + 16 * t + quad * 4 + r;
            float v = stt[t][r] + b4[t][r];
            if (key > query + CUR0) v = NEGBIG;
            p[r] = exp2f(v);
          }
          uint2 pw;
          pw.x = pk2(p[0], p[1]);
          pw.y = pk2(p[2], p[3]);
          *(uint2*)(PlW + (pwbase + ((32 * t + 8 * quad) ^ pxor))) = pw;
        }
      } else {
        for (int t = 0; t < 4; t++) {
          float p[4];
          for (int r = 0; r < 4; r++) p[r] = exp2f(stt[t][r] + b4[t][r]);
          uint2 pw;
          pw.x = pk2(p[0], p[1]);
          pw.y = pk2(p[2], p[3]);
          *(uint2*)(PlW + (pwbase + ((32 * t + 8 * quad) ^ pxor))) = pw;
        }
      }
      short8 pf[2];
      pf[0] = *(const short8*)(PlW + (pwbase + ((16 * quad) ^ pxor)));
      pf[1] = *(const short8*)(PlW + (pwbase + ((64 + 16 * quad) ^ pxor)));
      __builtin_amdgcn_s_setprio(1);
      for (int c = 0; c < 2; c++) {
        lacc = __builtin_amdgcn_mfma_f32_16x16x32_bf16(pf[c], ones, lacc, 0, 0, 0);
        for (int jd = 0; jd < 8; jd++) {
          int row = jd * 16 + l15;
          short8 vf = *(const short8*)&VtB[row * 64 + (((c * 4 + quad) ^ (row & 7))) * 8];
          o[jd] = __builtin_amdgcn_mfma_f32_16x16x32_bf16(pf[c], vf, o[jd], 0, 0, 0);
        }
      }
      __builtin_amdgcn_s_setprio(0);
    }
  }

  // lacc[r] = sum_k P[query = wq0+quad*4+r][k]  (same layout as o rows)
  f32x4 linv;
  for (int r = 0; r < 4; r++) linv[r] = 1.0f / lacc[r];
  for (int r = 0; r < 4; r++) {
    int qrow = wq0 + quad * 4 + r;
    unsigned short* op = attnOut + (long)qrow * DMODEL + h * HD;
    for (int jd = 0; jd < 8; jd++) op[jd * 16 + l15] = f2bf(o[jd][r] * linv[r]);
  }
}

// ---------------- launcher ----------------
extern "C" void kernel_launch(void* const* d_in, const int* in_sizes, int n_in,
                              void* d_out, int out_size, void* d_ws, size_t ws_size,
                              hipStream_t stream) {
  (void)in_sizes; (void)n_in; (void)out_size; (void)ws_size;
  const float* hidden    = (const float*)d_in[0];
  const float* sink_k    = (const float*)d_in[1];
  const float* sink_v    = (const float*)d_in[2];
  const float* win_k     = (const float*)d_in[3];
  const float* win_v     = (const float*)d_in[4];
  const int*   sink_pos  = (const int*)d_in[5];
  const int*   key_pos   = (const int*)d_in[6];
  const float* sink_mask = (const float*)d_in[7];
  const float* key_mask  = (const float*)d_in[8];
  const float* Wq = (const float*)d_in[9];
  const float* Wk = (const float*)d_in[10];
  const float* Wv = (const float*)d_in[11];
  const float* Wo = (const float*)d_in[12];
  float* out = (float*)d_out;

  char* ws = (char*)d_ws;
  unsigned short* hidB  = (unsigned short*)(ws + 0);           // 16.8 MB; attn reuses
  unsigned short* attn  = (unsigned short*)(ws + 0);
  unsigned short* WoT   = (unsigned short*)(ws + 16777216L);   // 33.5 MB
  unsigned short* WqkvT = (unsigned short*)(ws + 50331648L);   // 50.3 MB
  unsigned short* Qb    = (unsigned short*)(ws + 100663296L);  // 16.8 MB
  unsigned short* Kb    = (unsigned short*)(ws + 117440512L);  // 8.65 MB
  unsigned short* VTb   = (unsigned short*)(ws + 126091264L);  // 8.65 MB
  float2* postab        = (float2*)(ws + 134742016L);          // 1 MB
  float* bias           = (float*)(ws + 135790592L);           // 16.9 KB
  int* maxp             = (int*)(ws + 135807488L);

  maxpos_kernel<<<1, 256, 0, stream>>>(sink_pos, key_pos, maxp);
  bias_kernel<<<(KT_PAD + 255) / 256, 256, 0, stream>>>(sink_mask, key_mask, bias);
  postab_kernel<<<QLEN, 64, 0, stream>>>(maxp, postab);
  cvt_kernel<<<(QLEN * DMODEL / 4) / 256, 256, 0, stream>>>(hidden, hidB);
  transpose_all<<<dim3(320, 128), dim3(32, 8), 0, stream>>>(Wq, Wk, Wv, Wo, WqkvT, WoT);

  gemm_qkv<<<dim3(48, 16), 256, 0, stream>>>(hidB, WqkvT, postab, Qb, Kb, VTb);

  rope_cache<<<dim3(CUR0, NKV), 128, 0, stream>>>(sink_k, win_k, sink_pos, key_pos, Kb);
  scatter_cache<<<dim3(65, 4, NKV), dim3(32, 8), 0, stream>>>(sink_v, win_v, VTb);
  pad_zero<<<(NKV * (KT_PAD - KTOT) * HD + 255) / 256, 256, 0, stream>>>(Kb, VTb);

  attn_kernel<<<dim3(32, 16), 512, 0, stream>>>(Qb, Kb, VTb, bias, attn);

  gemm_bt<<<dim3(32, 16), 256, 0, stream>>>(attn, WoT, out, QLEN, DMODEL, DMODEL);
}

// Round 4
// 618.235 us; speedup vs baseline: 1.2402x; 1.0018x over previous
//
#include <hip/hip_runtime.h>
#include <hip/hip_bf16.h>

typedef __attribute__((ext_vector_type(8))) short short8;
typedef __attribute__((ext_vector_type(4))) float f32x4;
typedef __attribute__((ext_vector_type(4))) unsigned short us4;

#define DEV static __device__ __forceinline__

constexpr int QLEN = 2048;
constexpr int DMODEL = 4096;
constexpr int NHEAD = 32;
constexpr int NKV = 8;
constexpr int HD = 128;
constexpr int NSINK = 4;
constexpr int NWIN = 2048;
constexpr int CUR0 = NSINK + NWIN;     // 2052
constexpr int KTOT = CUR0 + QLEN;      // 4100
constexpr int KT_PAD = 4224;           // 66 * 64
constexpr float LOG2E = 1.4426950408889634f;
constexpr float NEGBIG = -1.0e30f;
constexpr float MSHIFT = 32.0f;        // fixed softmax shift (log2 units)
constexpr float QSCALE = 0.08838834764831843f * LOG2E; // 1/sqrt(128) * log2(e)

DEV unsigned short f2bf(float f) {
  unsigned int u = __float_as_uint(f);
  u += 0x7fffu + ((u >> 16) & 1u);
  return (unsigned short)(u >> 16);
}

DEV unsigned int pk2(float a, float b) {   // packed bf16 pair, RNE (v_cvt_pk_bf16_f32)
  __hip_bfloat162 h = __float22bfloat162_rn(make_float2(a, b));
  return *(unsigned int*)&h;
}

DEV void gld16(const void* g, void* l) {
  __builtin_amdgcn_global_load_lds((const __attribute__((address_space(1))) void*)g,
                                   (__attribute__((address_space(3))) void*)l, 16, 0, 0);
}

// ---------------- small prep kernels ----------------

__global__ void maxpos_kernel(const int* __restrict__ sp, const int* __restrict__ kp,
                              int* __restrict__ outp) {
  __shared__ int red[256];
  int t = threadIdx.x;
  int m = -0x7fffffff;
  for (int i = t; i < NSINK; i += 256) m = max(m, sp[i]);
  for (int i = t; i < NWIN; i += 256) m = max(m, kp[i]);
  red[t] = m;
  __syncthreads();
  for (int s = 128; s > 0; s >>= 1) {
    if (t < s) red[t] = max(red[t], red[t + s]);
    __syncthreads();
  }
  if (t == 0) outp[0] = red[0] + 1;
}

__global__ void bias_kernel(const float* __restrict__ sm, const float* __restrict__ km,
                            float* __restrict__ bias) {
  int kk = blockIdx.x * 256 + threadIdx.x;
  if (kk >= KT_PAD) return;
  float b;
  if (kk < NSINK) b = sm[kk] * NEGBIG * LOG2E - MSHIFT;
  else if (kk < CUR0) b = km[kk - NSINK] * NEGBIG * LOG2E - MSHIFT;
  else if (kk < KTOT) b = -MSHIFT;
  else b = NEGBIG;
  bias[kk] = b;
}

// cos/sin table for query positions: tab[q][j] = (cos,sin)((maxp+q) * invf(j))
__global__ void postab_kernel(const int* __restrict__ maxp, float2* __restrict__ tab) {
  int q = blockIdx.x, j = threadIdx.x;
  float pos = (float)(maxp[0] + q);
  float invf = exp2f(-(float)(2 * j) * (13.287712379549449f / 128.0f));
  float ang = pos * invf;
  tab[q * 64 + j] = make_float2(__cosf(ang), __sinf(ang));
}

__global__ __launch_bounds__(256) void cvt_kernel(const float* __restrict__ src,
                                                  unsigned short* __restrict__ dst) {
  long i = ((long)blockIdx.x * 256 + threadIdx.x) * 4;
  f32x4 v = *(const f32x4*)(src + i);
  us4 o;
  o[0] = f2bf(v[0]); o[1] = f2bf(v[1]); o[2] = f2bf(v[2]); o[3] = f2bf(v[3]);
  *(us4*)(dst + i) = o;
}

// all 4 weight transposes in one launch. x: [0,128)=Wq [128,160)=Wk [160,192)=Wv [192,320)=Wo
__global__ void transpose_all(const float* __restrict__ Wq, const float* __restrict__ Wk,
                              const float* __restrict__ Wv, const float* __restrict__ Wo,
                              unsigned short* __restrict__ WqkvT,
                              unsigned short* __restrict__ WoT) {
  __shared__ float t[32][33];
  int bx = blockIdx.x;
  const float* W; unsigned short* WT; int N; int xl;
  if (bx < 128)      { W = Wq; WT = WqkvT;                   N = 4096; xl = bx; }
  else if (bx < 160) { W = Wk; WT = WqkvT + 4096L * 4096;    N = 1024; xl = bx - 128; }
  else if (bx < 192) { W = Wv; WT = WqkvT + 5120L * 4096;    N = 1024; xl = bx - 160; }
  else               { W = Wo; WT = WoT;                     N = 4096; xl = bx - 192; }
  int n0 = xl * 32, k0 = blockIdx.y * 32;
  int tx = threadIdx.x, ty = threadIdx.y;
  for (int p = 0; p < 4; p++) {
    int k = k0 + ty + p * 8;
    t[ty + p * 8][tx] = W[(long)k * N + n0 + tx];
  }
  __syncthreads();
  for (int p = 0; p < 4; p++) {
    int n = n0 + ty + p * 8;
    WT[(long)n * 4096 + k0 + tx] = f2bf(t[tx][ty + p * 8]);
  }
}

// ---------------- generic GEMM (used for output projection, f32 C) ----------------
// Grid MUST be dim3(nx, 16) with nwg % 8 == 0. M-fastest XCD-chunked remap:
// consecutive tile ids within one XCD chunk share the Bt panel (L2-resident).
__global__ __launch_bounds__(256) void gemm_bt(const unsigned short* __restrict__ A,
                                               const unsigned short* __restrict__ Bt,
                                               float* __restrict__ C,
                                               int M, int N, int K) {
  __shared__ __align__(16) unsigned short As[128 * 64];
  __shared__ __align__(16) unsigned short Bs[128 * 64];
  int tid = threadIdx.x, lane = tid & 63, w = tid >> 6;
  int nwg = gridDim.x * gridDim.y;
  int orig = blockIdx.y * gridDim.x + blockIdx.x;
  int wg = (orig & 7) * (nwg >> 3) + (orig >> 3);   // XCD-chunked (nwg%8==0)
  int mx = wg & 15, nx = wg >> 4;                   // gridDim.y == 16, M fastest
  int m0 = mx * 128, n0 = nx * 128;
  int wm = w & 1, wn = w >> 1;
  f32x4 z = {0.f, 0.f, 0.f, 0.f};
  f32x4 acc[4][4];
  for (int i = 0; i < 4; i++) for (int j = 0; j < 4; j++) acc[i][j] = z;
  int nK = K >> 6;
  for (int ks = 0; ks < nK; ks++) {
    long k0 = (long)ks << 6;
    for (int t = 0; t < 4; t++) {
      int chunk = w * 4 + t;
      int row = chunk * 8 + (lane >> 3);
      int kbs = (lane & 7) ^ (row & 7);
      gld16(A + ((long)(m0 + row) * K + k0 + kbs * 8), &As[chunk * 512 + lane * 8]);
      gld16(Bt + ((long)(n0 + row) * K + k0 + kbs * 8), &Bs[chunk * 512 + lane * 8]);
    }
    __syncthreads();
    for (int kc = 0; kc < 2; kc++) {
      short8 af[4], bf[4];
      int c = kc * 4 + (lane >> 4);
      for (int i = 0; i < 4; i++) {
        int ra = wm * 64 + i * 16 + (lane & 15);
        af[i] = *(const short8*)&As[ra * 64 + (c ^ (ra & 7)) * 8];
        int rb = wn * 64 + i * 16 + (lane & 15);
        bf[i] = *(const short8*)&Bs[rb * 64 + (c ^ (rb & 7)) * 8];
      }
      for (int i = 0; i < 4; i++)
        for (int j = 0; j < 4; j++)
          acc[i][j] = __builtin_amdgcn_mfma_f32_16x16x32_bf16(af[i], bf[j], acc[i][j], 0, 0, 0);
    }
    __syncthreads();
  }
  for (int i = 0; i < 4; i++) {
    int m = m0 + wm * 64 + i * 16 + ((lane >> 4) << 2);
    for (int j = 0; j < 4; j++) {
      int n = n0 + wn * 64 + j * 16 + (lane & 15);
      float* cp = C + (long)m * N + n;
      for (int r = 0; r < 4; r++) cp[(long)r * N] = acc[i][j][r];
    }
  }
}

// ---------------- fused QKV GEMM + RoPE + scatter epilogue ----------------
// A=[2048][4096] bf16, Bt=[6144][4096] bf16. C-tile 128x128 aligns with heads:
// nb<32 -> Q head nb (rope, *QSCALE -> Qb); nb in[32,40) -> K-cur kvh nb-32
// (rope -> Kb at CUR0+); nb>=40 -> V kvh nb-40 (transpose -> VTb at CUR0+).
// Grid dim3(48,16); M-fastest XCD-chunked remap as in gemm_bt.
__global__ __launch_bounds__(256) void gemm_qkv(const unsigned short* __restrict__ A,
                                                const unsigned short* __restrict__ Bt,
                                                const float2* __restrict__ postab,
                                                unsigned short* __restrict__ Qb,
                                                unsigned short* __restrict__ Kb,
                                                unsigned short* __restrict__ VTb) {
  __shared__ __align__(16) char smem[66 * 512];           // 33 KB: staging / epilogue union
  unsigned short* As = (unsigned short*)smem;             // 16 KB
  unsigned short* Bs = As + 8192;                         // 16 KB
  float* Cs = (float*)smem;                               // 64 x 129 f32 = 33024 B
  constexpr int K = 4096;
  int tid = threadIdx.x, lane = tid & 63, w = tid >> 6;
  int quad = lane >> 4, l15 = lane & 15;
  int nwg = gridDim.x * gridDim.y;                        // 768
  int orig = blockIdx.y * gridDim.x + blockIdx.x;
  int wg = (orig & 7) * (nwg >> 3) + (orig >> 3);         // XCD-chunked
  int mx = wg & 15, nx = wg >> 4;                         // M fastest
  int m0 = mx * 128, n0 = nx * 128;
  int wm = w & 1, wn = w >> 1;
  f32x4 z = {0.f, 0.f, 0.f, 0.f};
  f32x4 acc[4][4];
  for (int i = 0; i < 4; i++) for (int j = 0; j < 4; j++) acc[i][j] = z;
  for (int ks = 0; ks < K / 64; ks++) {
    long k0 = (long)ks << 6;
    for (int t = 0; t < 4; t++) {
      int chunk = w * 4 + t;
      int row = chunk * 8 + (lane >> 3);
      int kbs = (lane & 7) ^ (row & 7);
      gld16(A + ((long)(m0 + row) * K + k0 + kbs * 8), &As[chunk * 512 + lane * 8]);
      gld16(Bt + ((long)(n0 + row) * K + k0 + kbs * 8), &Bs[chunk * 512 + lane * 8]);
    }
    __syncthreads();
    for (int kc = 0; kc < 2; kc++) {
      short8 af[4], bf[4];
      int c = kc * 4 + quad;
      for (int i = 0; i < 4; i++) {
        int ra = wm * 64 + i * 16 + l15;
        af[i] = *(const short8*)&As[ra * 64 + (c ^ (ra & 7)) * 8];
        int rb = wn * 64 + i * 16 + l15;
        bf[i] = *(const short8*)&Bs[rb * 64 + (c ^ (rb & 7)) * 8];
      }
      for (int i = 0; i < 4; i++)
        for (int j = 0; j < 4; j++)
          acc[i][j] = __builtin_amdgcn_mfma_f32_16x16x32_bf16(af[i], bf[j], acc[i][j], 0, 0, 0);
    }
    __syncthreads();
  }

  int nb = nx;
  int part = (nb < 32) ? 0 : (nb < 40 ? 1 : 2);
  int hh = (part == 0) ? nb : (part == 1 ? nb - 32 : nb - 40);
  float scale = (part == 0) ? QSCALE : 1.0f;

  for (int pass = 0; pass < 2; pass++) {
    __syncthreads();
    if (wm == pass) {
      for (int i = 0; i < 4; i++)
        for (int j = 0; j < 4; j++)
          for (int r = 0; r < 4; r++)
            Cs[(i * 16 + quad * 4 + r) * 129 + wn * 64 + j * 16 + l15] = acc[i][j][r];
    }
    __syncthreads();
    if (part < 2) {
      if (tid < 128) {
        int r = tid & 63, hf = tid >> 6;
        int query = m0 + pass * 64 + r;
        const float2* tb = postab + query * 64;
        unsigned short* dst = (part == 0)
            ? Qb + ((long)hh * QLEN + query) * HD + hf * 64
            : Kb + ((long)hh * KT_PAD + CUR0 + query) * HD + hf * 64;
        for (int j = 0; j < 64; j += 4) {
          float v[4];
          for (int u = 0; u < 4; u++) {
            float2 cs = tb[j + u];
            int d = hf * 64 + j + u;
            float xa = Cs[r * 129 + d];
            float xb = Cs[r * 129 + (d ^ 64)];
            v[u] = (xa * cs.x + (hf ? xb : -xb) * cs.y) * scale;
          }
          uint2 o4;
          o4.x = pk2(v[0], v[1]);
          o4.y = pk2(v[2], v[3]);
          *(uint2*)(dst + j) = o4;
        }
      }
    } else {
      if (tid < 128) {
        int d = tid;
        unsigned short* dst = VTb + ((long)hh * HD + d) * KT_PAD + CUR0 + m0 + pass * 64;
        for (int m = 0; m < 64; m += 4) {
          uint2 o4;
          o4.x = pk2(Cs[m * 129 + d], Cs[(m + 1) * 129 + d]);
          o4.y = pk2(Cs[(m + 2) * 129 + d], Cs[(m + 3) * 129 + d]);
          *(uint2*)(dst + m) = o4;
        }
      }
    }
  }
}

// ---------------- cache (sink + window) RoPE / V scatter ----------------
__global__ void rope_cache(const float* __restrict__ sink_k, const float* __restrict__ win_k,
                           const int* __restrict__ sp, const int* __restrict__ kp,
                           unsigned short* __restrict__ Kb) {
  int s = blockIdx.x, kvh = blockIdx.y, d = threadIdx.x;
  const float* src; int pos;
  if (s < NSINK) { src = sink_k + ((long)kvh * NSINK + s) * HD; pos = sp[s]; }
  else           { src = win_k + ((long)kvh * NWIN + (s - NSINK)) * HD; pos = kp[s - NSINK]; }
  float x = src[d];
  float x2 = src[d ^ 64];
  float rot = (d < 64) ? -x2 : x2;
  int i = d & 63;
  float invf = exp2f(-(float)(2 * i) * (13.287712379549449f / 128.0f));
  float ang = (float)pos * invf;
  float c = __cosf(ang), sn = __sinf(ang);
  Kb[((long)kvh * KT_PAD + s) * HD + d] = f2bf(x * c + rot * sn);
}

// x<64: window chunk; x==64: sinks
__global__ void scatter_cache(const float* __restrict__ sink_v, const float* __restrict__ win_v,
                              unsigned short* __restrict__ VTb) {
  __shared__ float t[32][33];
  int kvh = blockIdx.z, d0 = blockIdx.y * 32;
  const float* src; int S, s0, dstPos0;
  if (blockIdx.x < 64) { src = win_v + (long)kvh * NWIN * HD; S = NWIN; s0 = blockIdx.x * 32; dstPos0 = NSINK; }
  else                 { src = sink_v + (long)kvh * NSINK * HD; S = NSINK; s0 = 0; dstPos0 = 0; }
  int tx = threadIdx.x, ty = threadIdx.y;
  for (int p = 0; p < 4; p++) {
    int s = s0 + ty + p * 8;
    if (s < S) t[ty + p * 8][tx] = src[(long)s * HD + d0 + tx];
  }
  __syncthreads();
  for (int p = 0; p < 4; p++) {
    int d = d0 + ty + p * 8;
    int s = s0 + tx;
    if (s < S)
      VTb[((long)kvh * HD + d) * KT_PAD + dstPos0 + s] = f2bf(t[tx][ty + p * 8]);
  }
}

__global__ void pad_zero(unsigned short* __restrict__ Kb, unsigned short* __restrict__ VTb) {
  int idx = blockIdx.x * 256 + threadIdx.x;
  int total = NKV * (KT_PAD - KTOT) * HD;
  if (idx >= total) return;
  int per = (KT_PAD - KTOT) * HD;
  int kvh = idx / per;
  int rem = idx % per;
  int pos = KTOT + rem / HD;
  int d = rem % HD;
  Kb[((long)kvh * KT_PAD + pos) * HD + d] = 0;
  VTb[((long)kvh * HD + d) * KT_PAD + pos] = 0;
}

// ---------------- flash attention (8 waves, 16q/wave, hoisted addressing) ----------
// All LDS fragment addresses are loop-invariant (swizzle uses row&15==l15 for K,
// row&7==l15&7 for V); staging uses running global pointers; bias is folded into
// the QK MFMA C-init; QK is skipped for causally-inactive waves.
__global__ __launch_bounds__(512, 4) void attn_kernel(
    const unsigned short* __restrict__ Qb,
    const unsigned short* __restrict__ Kb,
    const unsigned short* __restrict__ VTb,
    const float* __restrict__ biasArr,
    unsigned short* __restrict__ attnOut) {
  // LDS = 32K (Kt) + 32K (Vt) + 16K (Pl) = 81920 B exactly -> 2 blocks/CU.
  __shared__ __align__(16) unsigned short Kt[2][64 * 128];
  __shared__ __align__(16) unsigned short Vt[2][128 * 64];
  __shared__ __align__(16) unsigned short Pl[8][1024];  // per-wave 16q x 64k bf16, XOR-swizzled
  int tid = threadIdx.x, lane = tid & 63, w = tid >> 6;
  int quad = lane >> 4, l15 = lane & 15;
  int hh = blockIdx.x;
  int h = (hh & 7) * 4 + (hh >> 3);
  int kvh = hh & 7;
  int yt = blockIdx.y;
  int qt = (yt < 8) ? yt : (23 - yt);
  int q0 = qt * 128;
  int wq0 = q0 + w * 16;                  // this wave's 16 queries

  short8 qf[4];
  for (int kc = 0; kc < 4; kc++) {
    long off = ((long)h * QLEN + wq0 + l15) * HD + kc * 32 + quad * 8;
    qf[kc] = *(const short8*)(Qb + off);
  }
  short8 ones;
  for (int i = 0; i < 8; i++) ones[i] = (short)0x3F80;  // bf16 1.0

  f32x4 z = {0.f, 0.f, 0.f, 0.f};
  f32x4 o[8];
  for (int j = 0; j < 8; j++) o[j] = z;
  f32x4 lacc = z;                          // softmax denominator via ones-MFMA

  int nsteps = min(KT_PAD / 64, (CUR0 + q0 + 127) / 64 + 1);
  const unsigned short* Kbase = Kb + (long)kvh * KT_PAD * HD;
  const unsigned short* Vbase = VTb + (long)kvh * HD * KT_PAD;

  // ---- hoisted staging pointers (advance by constant per step) ----
  const unsigned short* kg[2];
  const unsigned short* vg[2];
  unsigned short* kl[2];
  unsigned short* vl[2];
  for (int t = 0; t < 2; t++) {
    int chunk = w * 2 + t;                 // 0..15
    int krow = chunk * 4 + quad;           // 0..63
    int kkbs = l15 ^ (krow & 15);
    kg[t] = Kbase + (long)krow * HD + kkbs * 8;
    kl[t] = &Kt[0][chunk * 512 + lane * 8];
    int vrow = chunk * 8 + (lane >> 3);    // 0..127
    int vkbs = (lane & 7) ^ (vrow & 7);
    vg[t] = Vbase + (long)vrow * KT_PAD + vkbs * 8;
    vl[t] = &Vt[0][chunk * 512 + lane * 8];
  }
  // ---- hoisted LDS fragment read bases (step-invariant) ----
  const unsigned short* kra[4];            // K: row=16t+l15 -> t via imm offset
  for (int kc = 0; kc < 4; kc++)
    kra[kc] = &Kt[0][l15 * 128 + ((kc * 4 + quad) ^ l15) * 8];
  const unsigned short* vra[2];            // V: row=jd*16+l15 -> jd via imm offset
  for (int c = 0; c < 2; c++)
    vra[c] = &Vt[0][l15 * 64 + ((c * 4 + quad) ^ (l15 & 7)) * 8];
  // ---- hoisted P-tile LDS addresses ----
  char* PlW = (char*)&Pl[w][0];
  int pwbase = l15 * 128;
  int pxor = (l15 & 7) << 4;
  unsigned int pwa[4];
  for (int t = 0; t < 4; t++) pwa[t] = pwbase + ((32 * t + 8 * quad) ^ pxor);
  const short8* pra0 = (const short8*)(PlW + (pwbase + ((16 * quad) ^ pxor)));
  const short8* pra1 = (const short8*)(PlW + (pwbase + ((64 + 16 * quad) ^ pxor)));
  // ---- running bias pointer (bias folds into QK C-init) ----
  const float* bp = biasArr + quad * 4;

  // prologue: stage step 0 into buffer 0
  for (int t = 0; t < 2; t++) {
    gld16(kg[t], kl[t]);
    gld16(vg[t], vl[t]);
    kg[t] += 8192; vg[t] += 64;
  }

  for (int st = 0; st < nsteps; st++) {
    int k0 = st * 64;
    int cur = st & 1;
    __syncthreads();

    if (st + 1 < nsteps) {
      int nb = (cur ^ 1) << 13;            // shorts offset of next buffer
      for (int t = 0; t < 2; t++) {
        gld16(kg[t], kl[t] + nb);
        gld16(vg[t], vl[t] + nb);
        kg[t] += 8192; vg[t] += 64;
      }
    }

    if (k0 <= wq0 + 15 + CUR0) {
      int curo = cur << 13;                // shorts offset of current buffer

      f32x4 stt[4];
      for (int t = 0; t < 4; t++) stt[t] = *(const f32x4*)(bp + 16 * t);
      __builtin_amdgcn_s_setprio(1);
      for (int kc = 0; kc < 4; kc++) {
        for (int t = 0; t < 4; t++) {
          short8 kf = *(const short8*)(kra[kc] + curo + t * 2048);
          stt[t] = __builtin_amdgcn_mfma_f32_16x16x32_bf16(kf, qf[kc], stt[t], 0, 0, 0);
        }
      }
      __builtin_amdgcn_s_setprio(0);

      int query = wq0 + l15;
      bool needMask = k0 + 63 > wq0 + CUR0;
      if (needMask) {
        for (int t = 0; t < 4; t++) {
          float p[4];
          for (int r = 0; r < 4; r++) {
            int key = k0 + 16 * t + quad * 4 + r;
            float v = stt[t][r];
            if (key > query + CUR0) v = NEGBIG;
            p[r] = exp2f(v);
          }
          uint2 pw;
          pw.x = pk2(p[0], p[1]);
          pw.y = pk2(p[2], p[3]);
          *(uint2*)(PlW + pwa[t]) = pw;
        }
      } else {
        for (int t = 0; t < 4; t++) {
          float p[4];
          for (int r = 0; r < 4; r++) p[r] = exp2f(stt[t][r]);
          uint2 pw;
          pw.x = pk2(p[0], p[1]);
          pw.y = pk2(p[2], p[3]);
          *(uint2*)(PlW + pwa[t]) = pw;
        }
      }
      short8 pf0 = *pra0;
      short8 pf1 = *pra1;
      __builtin_amdgcn_s_setprio(1);
      lacc = __builtin_amdgcn_mfma_f32_16x16x32_bf16(pf0, ones, lacc, 0, 0, 0);
      for (int jd = 0; jd < 8; jd++) {
        short8 vf = *(const short8*)(vra[0] + curo + jd * 1024);
        o[jd] = __builtin_amdgcn_mfma_f32_16x16x32_bf16(pf0, vf, o[jd], 0, 0, 0);
      }
      lacc = __builtin_amdgcn_mfma_f32_16x16x32_bf16(pf1, ones, lacc, 0, 0, 0);
      for (int jd = 0; jd < 8; jd++) {
        short8 vf = *(const short8*)(vra[1] + curo + jd * 1024);
        o[jd] = __builtin_amdgcn_mfma_f32_16x16x32_bf16(pf1, vf, o[jd], 0, 0, 0);
      }
      __builtin_amdgcn_s_setprio(0);
    }
    bp += 64;
  }

  // lacc[r] = sum_k P[query = wq0+quad*4+r][k]  (same layout as o rows)
  f32x4 linv;
  for (int r = 0; r < 4; r++) linv[r] = 1.0f / lacc[r];
  for (int r = 0; r < 4; r++) {
    int qrow = wq0 + quad * 4 + r;
    unsigned short* op = attnOut + (long)qrow * DMODEL + h * HD;
    for (int jd = 0; jd < 8; jd++) op[jd * 16 + l15] = f2bf(o[jd][r] * linv[r]);
  }
}

// ---------------- launcher ----------------
extern "C" void kernel_launch(void* const* d_in, const int* in_sizes, int n_in,
                              void* d_out, int out_size, void* d_ws, size_t ws_size,
                              hipStream_t stream) {
  (void)in_sizes; (void)n_in; (void)out_size; (void)ws_size;
  const float* hidden    = (const float*)d_in[0];
  const float* sink_k    = (const float*)d_in[1];
  const float* sink_v    = (const float*)d_in[2];
  const float* win_k     = (const float*)d_in[3];
  const float* win_v     = (const float*)d_in[4];
  const int*   sink_pos  = (const int*)d_in[5];
  const int*   key_pos   = (const int*)d_in[6];
  const float* sink_mask = (const float*)d_in[7];
  const float* key_mask  = (const float*)d_in[8];
  const float* Wq = (const float*)d_in[9];
  const float* Wk = (const float*)d_in[10];
  const float* Wv = (const float*)d_in[11];
  const float* Wo = (const float*)d_in[12];
  float* out = (float*)d_out;

  char* ws = (char*)d_ws;
  unsigned short* hidB  = (unsigned short*)(ws + 0);           // 16.8 MB; attn reuses
  unsigned short* attn  = (unsigned short*)(ws + 0);
  unsigned short* WoT   = (unsigned short*)(ws + 16777216L);   // 33.5 MB
  unsigned short* WqkvT = (unsigned short*)(ws + 50331648L);   // 50.3 MB
  unsigned short* Qb    = (unsigned short*)(ws + 100663296L);  // 16.8 MB
  unsigned short* Kb    = (unsigned short*)(ws + 117440512L);  // 8.65 MB
  unsigned short* VTb   = (unsigned short*)(ws + 126091264L);  // 8.65 MB
  float2* postab        = (float2*)(ws + 134742016L);          // 1 MB
  float* bias           = (float*)(ws + 135790592L);           // 16.9 KB
  int* maxp             = (int*)(ws + 135807488L);

  maxpos_kernel<<<1, 256, 0, stream>>>(sink_pos, key_pos, maxp);
  bias_kernel<<<(KT_PAD + 255) / 256, 256, 0, stream>>>(sink_mask, key_mask, bias);
  postab_kernel<<<QLEN, 64, 0, stream>>>(maxp, postab);
  cvt_kernel<<<(QLEN * DMODEL / 4) / 256, 256, 0, stream>>>(hidden, hidB);
  transpose_all<<<dim3(320, 128), dim3(32, 8), 0, stream>>>(Wq, Wk, Wv, Wo, WqkvT, WoT);

  gemm_qkv<<<dim3(48, 16), 256, 0, stream>>>(hidB, WqkvT, postab, Qb, Kb, VTb);

  rope_cache<<<dim3(CUR0, NKV), 128, 0, stream>>>(sink_k, win_k, sink_pos, key_pos, Kb);
  scatter_cache<<<dim3(65, 4, NKV), dim3(32, 8), 0, stream>>>(sink_v, win_v, VTb);
  pad_zero<<<(NKV * (KT_PAD - KTOT) * HD + 255) / 256, 256, 0, stream>>>(Kb, VTb);

  attn_kernel<<<dim3(32, 16), 512, 0, stream>>>(Qb, Kb, VTb, bias, attn);

  gemm_bt<<<dim3(32, 16), 256, 0, stream>>>(attn, WoT, out, QLEN, DMODEL, DMODEL);
}

// Round 5
// 616.264 us; speedup vs baseline: 1.2442x; 1.0032x over previous
//
#include <hip/hip_runtime.h>
#include <hip/hip_bf16.h>

typedef __attribute__((ext_vector_type(8))) short short8;
typedef __attribute__((ext_vector_type(4))) float f32x4;
typedef __attribute__((ext_vector_type(4))) unsigned short us4;

#define DEV static __device__ __forceinline__

constexpr int QLEN = 2048;
constexpr int DMODEL = 4096;
constexpr int NHEAD = 32;
constexpr int NKV = 8;
constexpr int HD = 128;
constexpr int NSINK = 4;
constexpr int NWIN = 2048;
constexpr int CUR0 = NSINK + NWIN;     // 2052
constexpr int KTOT = CUR0 + QLEN;      // 4100
constexpr int KT_PAD = 4224;           // 66 * 64
constexpr float LOG2E = 1.4426950408889634f;
constexpr float NEGBIG = -1.0e30f;
constexpr float MSHIFT = 32.0f;        // fixed softmax shift (log2 units)
constexpr float QSCALE = 0.08838834764831843f * LOG2E; // 1/sqrt(128) * log2(e)

DEV unsigned short f2bf(float f) {
  unsigned int u = __float_as_uint(f);
  u += 0x7fffu + ((u >> 16) & 1u);
  return (unsigned short)(u >> 16);
}

DEV unsigned int pk2(float a, float b) {   // packed bf16 pair, RNE (v_cvt_pk_bf16_f32)
  __hip_bfloat162 h = __float22bfloat162_rn(make_float2(a, b));
  return *(unsigned int*)&h;
}

DEV void gld16(const void* g, void* l) {
  __builtin_amdgcn_global_load_lds((const __attribute__((address_space(1))) void*)g,
                                   (__attribute__((address_space(3))) void*)l, 16, 0, 0);
}

// ---------------- small prep kernels ----------------

__global__ void maxpos_kernel(const int* __restrict__ sp, const int* __restrict__ kp,
                              int* __restrict__ outp) {
  __shared__ int red[256];
  int t = threadIdx.x;
  int m = -0x7fffffff;
  for (int i = t; i < NSINK; i += 256) m = max(m, sp[i]);
  for (int i = t; i < NWIN; i += 256) m = max(m, kp[i]);
  red[t] = m;
  __syncthreads();
  for (int s = 128; s > 0; s >>= 1) {
    if (t < s) red[t] = max(red[t], red[t + s]);
    __syncthreads();
  }
  if (t == 0) outp[0] = red[0] + 1;
}

__global__ void bias_kernel(const float* __restrict__ sm, const float* __restrict__ km,
                            float* __restrict__ bias) {
  int kk = blockIdx.x * 256 + threadIdx.x;
  if (kk >= KT_PAD) return;
  float b;
  if (kk < NSINK) b = sm[kk] * NEGBIG * LOG2E - MSHIFT;
  else if (kk < CUR0) b = km[kk - NSINK] * NEGBIG * LOG2E - MSHIFT;
  else if (kk < KTOT) b = -MSHIFT;
  else b = NEGBIG;
  bias[kk] = b;
}

// cos/sin table for query positions: tab[q][j] = (cos,sin)((maxp+q) * invf(j))
__global__ void postab_kernel(const int* __restrict__ maxp, float2* __restrict__ tab) {
  int q = blockIdx.x, j = threadIdx.x;
  float pos = (float)(maxp[0] + q);
  float invf = exp2f(-(float)(2 * j) * (13.287712379549449f / 128.0f));
  float ang = pos * invf;
  tab[q * 64 + j] = make_float2(__cosf(ang), __sinf(ang));
}

__global__ __launch_bounds__(256) void cvt_kernel(const float* __restrict__ src,
                                                  unsigned short* __restrict__ dst) {
  long i = ((long)blockIdx.x * 256 + threadIdx.x) * 4;
  f32x4 v = *(const f32x4*)(src + i);
  us4 o;
  o[0] = f2bf(v[0]); o[1] = f2bf(v[1]); o[2] = f2bf(v[2]); o[3] = f2bf(v[3]);
  *(us4*)(dst + i) = o;
}

// all 4 weight transposes in one launch. x: [0,128)=Wq [128,160)=Wk [160,192)=Wv [192,320)=Wo
__global__ void transpose_all(const float* __restrict__ Wq, const float* __restrict__ Wk,
                              const float* __restrict__ Wv, const float* __restrict__ Wo,
                              unsigned short* __restrict__ WqkvT,
                              unsigned short* __restrict__ WoT) {
  __shared__ float t[32][33];
  int bx = blockIdx.x;
  const float* W; unsigned short* WT; int N; int xl;
  if (bx < 128)      { W = Wq; WT = WqkvT;                   N = 4096; xl = bx; }
  else if (bx < 160) { W = Wk; WT = WqkvT + 4096L * 4096;    N = 1024; xl = bx - 128; }
  else if (bx < 192) { W = Wv; WT = WqkvT + 5120L * 4096;    N = 1024; xl = bx - 160; }
  else               { W = Wo; WT = WoT;                     N = 4096; xl = bx - 192; }
  int n0 = xl * 32, k0 = blockIdx.y * 32;
  int tx = threadIdx.x, ty = threadIdx.y;
  for (int p = 0; p < 4; p++) {
    int k = k0 + ty + p * 8;
    t[ty + p * 8][tx] = W[(long)k * N + n0 + tx];
  }
  __syncthreads();
  for (int p = 0; p < 4; p++) {
    int n = n0 + ty + p * 8;
    WT[(long)n * 4096 + k0 + tx] = f2bf(t[tx][ty + p * 8]);
  }
}

// ---------------- generic GEMM (output projection, f32 C) ----------------
// Grid MUST be dim3(nx, 16) with nwg % 8 == 0. M-fastest XCD-chunked remap.
// 2-phase pipelined: double-buffered LDS, STAGE(k+1) issued BEFORE compute(k),
// single barrier per iteration (drains stage(k) + protects buf reuse).
__global__ __launch_bounds__(256) void gemm_bt(const unsigned short* __restrict__ A,
                                               const unsigned short* __restrict__ Bt,
                                               float* __restrict__ C,
                                               int M, int N, int K) {
  __shared__ __align__(16) unsigned short As[2][128 * 64];
  __shared__ __align__(16) unsigned short Bs[2][128 * 64];
  int tid = threadIdx.x, lane = tid & 63, w = tid >> 6;
  int nwg = gridDim.x * gridDim.y;
  int orig = blockIdx.y * gridDim.x + blockIdx.x;
  int wg = (orig & 7) * (nwg >> 3) + (orig >> 3);   // XCD-chunked (nwg%8==0)
  int mx = wg & 15, nx = wg >> 4;                   // gridDim.y == 16, M fastest
  int m0 = mx * 128, n0 = nx * 128;
  int wm = w & 1, wn = w >> 1;
  f32x4 z = {0.f, 0.f, 0.f, 0.f};
  f32x4 acc[4][4];
  for (int i = 0; i < 4; i++) for (int j = 0; j < 4; j++) acc[i][j] = z;
  int nK = K >> 6;

  const unsigned short* ag[4];
  const unsigned short* bg[4];
  unsigned short* al[4];
  unsigned short* bl[4];
  for (int t = 0; t < 4; t++) {
    int chunk = w * 4 + t;
    int row = chunk * 8 + (lane >> 3);
    int kbs = (lane & 7) ^ (row & 7);
    ag[t] = A + (long)(m0 + row) * K + kbs * 8;
    bg[t] = Bt + (long)(n0 + row) * K + kbs * 8;
    al[t] = &As[0][chunk * 512 + lane * 8];
    bl[t] = &Bs[0][chunk * 512 + lane * 8];
  }
  for (int t = 0; t < 4; t++) {            // prologue: stage ks=0 into buf 0
    gld16(ag[t], al[t]);
    gld16(bg[t], bl[t]);
    ag[t] += 64; bg[t] += 64;
  }
  int cur = 0;
  for (int ks = 0; ks < nK; ks++) {
    __syncthreads();                       // drains stage(ks); protects buf(cur^1)
    if (ks + 1 < nK) {
      int nb = (cur ^ 1) << 13;            // 8192 shorts per buffer
      for (int t = 0; t < 4; t++) {
        gld16(ag[t], al[t] + nb);
        gld16(bg[t], bl[t] + nb);
        ag[t] += 64; bg[t] += 64;
      }
    }
    const unsigned short* Ab = As[cur];
    const unsigned short* Bb = Bs[cur];
    for (int kc = 0; kc < 2; kc++) {
      short8 af[4], bf[4];
      int c = kc * 4 + (lane >> 4);
      for (int i = 0; i < 4; i++) {
        int ra = wm * 64 + i * 16 + (lane & 15);
        af[i] = *(const short8*)&Ab[ra * 64 + (c ^ (ra & 7)) * 8];
        int rb = wn * 64 + i * 16 + (lane & 15);
        bf[i] = *(const short8*)&Bb[rb * 64 + (c ^ (rb & 7)) * 8];
      }
      for (int i = 0; i < 4; i++)
        for (int j = 0; j < 4; j++)
          acc[i][j] = __builtin_amdgcn_mfma_f32_16x16x32_bf16(af[i], bf[j], acc[i][j], 0, 0, 0);
    }
    cur ^= 1;
  }
  for (int i = 0; i < 4; i++) {
    int m = m0 + wm * 64 + i * 16 + ((lane >> 4) << 2);
    for (int j = 0; j < 4; j++) {
      int n = n0 + wn * 64 + j * 16 + (lane & 15);
      float* cp = C + (long)m * N + n;
      for (int r = 0; r < 4; r++) cp[(long)r * N] = acc[i][j][r];
    }
  }
}

// ---------------- fused QKV GEMM + RoPE + scatter epilogue ----------------
// A=[2048][4096] bf16, Bt=[6144][4096] bf16. C-tile 128x128 aligns with heads:
// nb<32 -> Q head nb (rope, *QSCALE -> Qb); nb in[32,40) -> K-cur kvh nb-32
// (rope -> Kb at CUR0+); nb>=40 -> V kvh nb-40 (transpose -> VTb at CUR0+).
// Grid dim3(48,16); M-fastest XCD-chunked remap; 2-phase pipelined like gemm_bt.
// LDS: 64 KB staging (2x(As+Bs)); epilogue Cs (33 KB) unions into it after K-loop.
__global__ __launch_bounds__(256) void gemm_qkv(const unsigned short* __restrict__ A,
                                                const unsigned short* __restrict__ Bt,
                                                const float2* __restrict__ postab,
                                                unsigned short* __restrict__ Qb,
                                                unsigned short* __restrict__ Kb,
                                                unsigned short* __restrict__ VTb) {
  __shared__ __align__(16) unsigned short smem[4][8192];  // 64 KB
  unsigned short* As0 = &smem[0][0];                      // [2][8192]
  unsigned short* Bs0 = &smem[2][0];                      // [2][8192]
  float* Cs = (float*)smem;                               // 64 x 129 f32 = 33024 B
  constexpr int K = 4096;
  int tid = threadIdx.x, lane = tid & 63, w = tid >> 6;
  int quad = lane >> 4, l15 = lane & 15;
  int nwg = gridDim.x * gridDim.y;                        // 768
  int orig = blockIdx.y * gridDim.x + blockIdx.x;
  int wg = (orig & 7) * (nwg >> 3) + (orig >> 3);         // XCD-chunked
  int mx = wg & 15, nx = wg >> 4;                         // M fastest
  int m0 = mx * 128, n0 = nx * 128;
  int wm = w & 1, wn = w >> 1;
  f32x4 z = {0.f, 0.f, 0.f, 0.f};
  f32x4 acc[4][4];
  for (int i = 0; i < 4; i++) for (int j = 0; j < 4; j++) acc[i][j] = z;

  const unsigned short* ag[4];
  const unsigned short* bg[4];
  unsigned short* al[4];
  unsigned short* bl[4];
  for (int t = 0; t < 4; t++) {
    int chunk = w * 4 + t;
    int row = chunk * 8 + (lane >> 3);
    int kbs = (lane & 7) ^ (row & 7);
    ag[t] = A + (long)(m0 + row) * K + kbs * 8;
    bg[t] = Bt + (long)(n0 + row) * K + kbs * 8;
    al[t] = As0 + chunk * 512 + lane * 8;
    bl[t] = Bs0 + chunk * 512 + lane * 8;
  }
  for (int t = 0; t < 4; t++) {            // prologue
    gld16(ag[t], al[t]);
    gld16(bg[t], bl[t]);
    ag[t] += 64; bg[t] += 64;
  }
  int cur = 0;
  for (int ks = 0; ks < K / 64; ks++) {
    __syncthreads();
    if (ks + 1 < K / 64) {
      int nb = (cur ^ 1) << 13;
      for (int t = 0; t < 4; t++) {
        gld16(ag[t], al[t] + nb);
        gld16(bg[t], bl[t] + nb);
        ag[t] += 64; bg[t] += 64;
      }
    }
    const unsigned short* Ab = As0 + (cur << 13);
    const unsigned short* Bb = Bs0 + (cur << 13);
    for (int kc = 0; kc < 2; kc++) {
      short8 af[4], bf[4];
      int c = kc * 4 + quad;
      for (int i = 0; i < 4; i++) {
        int ra = wm * 64 + i * 16 + l15;
        af[i] = *(const short8*)&Ab[ra * 64 + (c ^ (ra & 7)) * 8];
        int rb = wn * 64 + i * 16 + l15;
        bf[i] = *(const short8*)&Bb[rb * 64 + (c ^ (rb & 7)) * 8];
      }
      for (int i = 0; i < 4; i++)
        for (int j = 0; j < 4; j++)
          acc[i][j] = __builtin_amdgcn_mfma_f32_16x16x32_bf16(af[i], bf[j], acc[i][j], 0, 0, 0);
    }
    cur ^= 1;
  }

  int nb = nx;
  int part = (nb < 32) ? 0 : (nb < 40 ? 1 : 2);
  int hh = (part == 0) ? nb : (part == 1 ? nb - 32 : nb - 40);
  float scale = (part == 0) ? QSCALE : 1.0f;

  for (int pass = 0; pass < 2; pass++) {
    __syncthreads();
    if (wm == pass) {
      for (int i = 0; i < 4; i++)
        for (int j = 0; j < 4; j++)
          for (int r = 0; r < 4; r++)
            Cs[(i * 16 + quad * 4 + r) * 129 + wn * 64 + j * 16 + l15] = acc[i][j][r];
    }
    __syncthreads();
    if (part < 2) {
      if (tid < 128) {
        int r = tid & 63, hf = tid >> 6;
        int query = m0 + pass * 64 + r;
        const float2* tb = postab + query * 64;
        unsigned short* dst = (part == 0)
            ? Qb + ((long)hh * QLEN + query) * HD + hf * 64
            : Kb + ((long)hh * KT_PAD + CUR0 + query) * HD + hf * 64;
        for (int j = 0; j < 64; j += 4) {
          float v[4];
          for (int u = 0; u < 4; u++) {
            float2 cs = tb[j + u];
            int d = hf * 64 + j + u;
            float xa = Cs[r * 129 + d];
            float xb = Cs[r * 129 + (d ^ 64)];
            v[u] = (xa * cs.x + (hf ? xb : -xb) * cs.y) * scale;
          }
          uint2 o4;
          o4.x = pk2(v[0], v[1]);
          o4.y = pk2(v[2], v[3]);
          *(uint2*)(dst + j) = o4;
        }
      }
    } else {
      if (tid < 128) {
        int d = tid;
        unsigned short* dst = VTb + ((long)hh * HD + d) * KT_PAD + CUR0 + m0 + pass * 64;
        for (int m = 0; m < 64; m += 4) {
          uint2 o4;
          o4.x = pk2(Cs[m * 129 + d], Cs[(m + 1) * 129 + d]);
          o4.y = pk2(Cs[(m + 2) * 129 + d], Cs[(m + 3) * 129 + d]);
          *(uint2*)(dst + m) = o4;
        }
      }
    }
  }
}

// ---------------- cache (sink + window) RoPE / V scatter ----------------
__global__ void rope_cache(const float* __restrict__ sink_k, const float* __restrict__ win_k,
                           const int* __restrict__ sp, const int* __restrict__ kp,
                           unsigned short* __restrict__ Kb) {
  int s = blockIdx.x, kvh = blockIdx.y, d = threadIdx.x;
  const float* src; int pos;
  if (s < NSINK) { src = sink_k + ((long)kvh * NSINK + s) * HD; pos = sp[s]; }
  else           { src = win_k + ((long)kvh * NWIN + (s - NSINK)) * HD; pos = kp[s - NSINK]; }
  float x = src[d];
  float x2 = src[d ^ 64];
  float rot = (d < 64) ? -x2 : x2;
  int i = d & 63;
  float invf = exp2f(-(float)(2 * i) * (13.287712379549449f / 128.0f));
  float ang = (float)pos * invf;
  float c = __cosf(ang), sn = __sinf(ang);
  Kb[((long)kvh * KT_PAD + s) * HD + d] = f2bf(x * c + rot * sn);
}

// x<64: window chunk; x==64: sinks
__global__ void scatter_cache(const float* __restrict__ sink_v, const float* __restrict__ win_v,
                              unsigned short* __restrict__ VTb) {
  __shared__ float t[32][33];
  int kvh = blockIdx.z, d0 = blockIdx.y * 32;
  const float* src; int S, s0, dstPos0;
  if (blockIdx.x < 64) { src = win_v + (long)kvh * NWIN * HD; S = NWIN; s0 = blockIdx.x * 32; dstPos0 = NSINK; }
  else                 { src = sink_v + (long)kvh * NSINK * HD; S = NSINK; s0 = 0; dstPos0 = 0; }
  int tx = threadIdx.x, ty = threadIdx.y;
  for (int p = 0; p < 4; p++) {
    int s = s0 + ty + p * 8;
    if (s < S) t[ty + p * 8][tx] = src[(long)s * HD + d0 + tx];
  }
  __syncthreads();
  for (int p = 0; p < 4; p++) {
    int d = d0 + ty + p * 8;
    int s = s0 + tx;
    if (s < S)
      VTb[((long)kvh * HD + d) * KT_PAD + dstPos0 + s] = f2bf(t[tx][ty + p * 8]);
  }
}

__global__ void pad_zero(unsigned short* __restrict__ Kb, unsigned short* __restrict__ VTb) {
  int idx = blockIdx.x * 256 + threadIdx.x;
  int total = NKV * (KT_PAD - KTOT) * HD;
  if (idx >= total) return;
  int per = (KT_PAD - KTOT) * HD;
  int kvh = idx / per;
  int rem = idx % per;
  int pos = KTOT + rem / HD;
  int d = rem % HD;
  Kb[((long)kvh * KT_PAD + pos) * HD + d] = 0;
  VTb[((long)kvh * HD + d) * KT_PAD + pos] = 0;
}

// ---------------- flash attention (8 waves, 16q/wave, hoisted addressing) ----------
// All LDS fragment addresses are loop-invariant (swizzle uses row&15==l15 for K,
// row&7==l15&7 for V); staging uses running global pointers; bias is folded into
// the QK MFMA C-init; QK is skipped for causally-inactive waves.
__global__ __launch_bounds__(512, 4) void attn_kernel(
    const unsigned short* __restrict__ Qb,
    const unsigned short* __restrict__ Kb,
    const unsigned short* __restrict__ VTb,
    const float* __restrict__ biasArr,
    unsigned short* __restrict__ attnOut) {
  // LDS = 32K (Kt) + 32K (Vt) + 16K (Pl) = 81920 B exactly -> 2 blocks/CU.
  __shared__ __align__(16) unsigned short Kt[2][64 * 128];
  __shared__ __align__(16) unsigned short Vt[2][128 * 64];
  __shared__ __align__(16) unsigned short Pl[8][1024];  // per-wave 16q x 64k bf16, XOR-swizzled
  int tid = threadIdx.x, lane = tid & 63, w = tid >> 6;
  int quad = lane >> 4, l15 = lane & 15;
  int hh = blockIdx.x;
  int h = (hh & 7) * 4 + (hh >> 3);
  int kvh = hh & 7;
  int yt = blockIdx.y;
  int qt = (yt < 8) ? yt : (23 - yt);
  int q0 = qt * 128;
  int wq0 = q0 + w * 16;                  // this wave's 16 queries

  short8 qf[4];
  for (int kc = 0; kc < 4; kc++) {
    long off = ((long)h * QLEN + wq0 + l15) * HD + kc * 32 + quad * 8;
    qf[kc] = *(const short8*)(Qb + off);
  }
  short8 ones;
  for (int i = 0; i < 8; i++) ones[i] = (short)0x3F80;  // bf16 1.0

  f32x4 z = {0.f, 0.f, 0.f, 0.f};
  f32x4 o[8];
  for (int j = 0; j < 8; j++) o[j] = z;
  f32x4 lacc = z;                          // softmax denominator via ones-MFMA

  int nsteps = min(KT_PAD / 64, (CUR0 + q0 + 127) / 64 + 1);
  const unsigned short* Kbase = Kb + (long)kvh * KT_PAD * HD;
  const unsigned short* Vbase = VTb + (long)kvh * HD * KT_PAD;

  // ---- hoisted staging pointers (advance by constant per step) ----
  const unsigned short* kg[2];
  const unsigned short* vg[2];
  unsigned short* kl[2];
  unsigned short* vl[2];
  for (int t = 0; t < 2; t++) {
    int chunk = w * 2 + t;                 // 0..15
    int krow = chunk * 4 + quad;           // 0..63
    int kkbs = l15 ^ (krow & 15);
    kg[t] = Kbase + (long)krow * HD + kkbs * 8;
    kl[t] = &Kt[0][chunk * 512 + lane * 8];
    int vrow = chunk * 8 + (lane >> 3);    // 0..127
    int vkbs = (lane & 7) ^ (vrow & 7);
    vg[t] = Vbase + (long)vrow * KT_PAD + vkbs * 8;
    vl[t] = &Vt[0][chunk * 512 + lane * 8];
  }
  // ---- hoisted LDS fragment read bases (step-invariant) ----
  const unsigned short* kra[4];            // K: row=16t+l15 -> t via imm offset
  for (int kc = 0; kc < 4; kc++)
    kra[kc] = &Kt[0][l15 * 128 + ((kc * 4 + quad) ^ l15) * 8];
  const unsigned short* vra[2];            // V: row=jd*16+l15 -> jd via imm offset
  for (int c = 0; c < 2; c++)
    vra[c] = &Vt[0][l15 * 64 + ((c * 4 + quad) ^ (l15 & 7)) * 8];
  // ---- hoisted P-tile LDS addresses ----
  char* PlW = (char*)&Pl[w][0];
  int pwbase = l15 * 128;
  int pxor = (l15 & 7) << 4;
  unsigned int pwa[4];
  for (int t = 0; t < 4; t++) pwa[t] = pwbase + ((32 * t + 8 * quad) ^ pxor);
  const short8* pra0 = (const short8*)(PlW + (pwbase + ((16 * quad) ^ pxor)));
  const short8* pra1 = (const short8*)(PlW + (pwbase + ((64 + 16 * quad) ^ pxor)));
  // ---- running bias pointer (bias folds into QK C-init) ----
  const float* bp = biasArr + quad * 4;

  // prologue: stage step 0 into buffer 0
  for (int t = 0; t < 2; t++) {
    gld16(kg[t], kl[t]);
    gld16(vg[t], vl[t]);
    kg[t] += 8192; vg[t] += 64;
  }

  for (int st = 0; st < nsteps; st++) {
    int k0 = st * 64;
    int cur = st & 1;
    __syncthreads();

    if (st + 1 < nsteps) {
      int nb = (cur ^ 1) << 13;            // shorts offset of next buffer
      for (int t = 0; t < 2; t++) {
        gld16(kg[t], kl[t] + nb);
        gld16(vg[t], vl[t] + nb);
        kg[t] += 8192; vg[t] += 64;
      }
    }

    if (k0 <= wq0 + 15 + CUR0) {
      int curo = cur << 13;                // shorts offset of current buffer

      f32x4 stt[4];
      for (int t = 0; t < 4; t++) stt[t] = *(const f32x4*)(bp + 16 * t);
      __builtin_amdgcn_s_setprio(1);
      for (int kc = 0; kc < 4; kc++) {
        for (int t = 0; t < 4; t++) {
          short8 kf = *(const short8*)(kra[kc] + curo + t * 2048);
          stt[t] = __builtin_amdgcn_mfma_f32_16x16x32_bf16(kf, qf[kc], stt[t], 0, 0, 0);
        }
      }
      __builtin_amdgcn_s_setprio(0);

      int query = wq0 + l15;
      bool needMask = k0 + 63 > wq0 + CUR0;
      if (needMask) {
        for (int t = 0; t < 4; t++) {
          float p[4];
          for (int r = 0; r < 4; r++) {
            int key = k0 + 16 * t + quad * 4 + r;
            float v = stt[t][r];
            if (key > query + CUR0) v = NEGBIG;
            p[r] = exp2f(v);
          }
          uint2 pw;
          pw.x = pk2(p[0], p[1]);
          pw.y = pk2(p[2], p[3]);
          *(uint2*)(PlW + pwa[t]) = pw;
        }
      } else {
        for (int t = 0; t < 4; t++) {
          float p[4];
          for (int r = 0; r < 4; r++) p[r] = exp2f(stt[t][r]);
          uint2 pw;
          pw.x = pk2(p[0], p[1]);
          pw.y = pk2(p[2], p[3]);
          *(uint2*)(PlW + pwa[t]) = pw;
        }
      }
      short8 pf0 = *pra0;
      short8 pf1 = *pra1;
      __builtin_amdgcn_s_setprio(1);
      lacc = __builtin_amdgcn_mfma_f32_16x16x32_bf16(pf0, ones, lacc, 0, 0, 0);
      for (int jd = 0; jd < 8; jd++) {
        short8 vf = *(const short8*)(vra[0] + curo + jd * 1024);
        o[jd] = __builtin_amdgcn_mfma_f32_16x16x32_bf16(pf0, vf, o[jd], 0, 0, 0);
      }
      lacc = __builtin_amdgcn_mfma_f32_16x16x32_bf16(pf1, ones, lacc, 0, 0, 0);
      for (int jd = 0; jd < 8; jd++) {
        short8 vf = *(const short8*)(vra[1] + curo + jd * 1024);
        o[jd] = __builtin_amdgcn_mfma_f32_16x16x32_bf16(pf1, vf, o[jd], 0, 0, 0);
      }
      __builtin_amdgcn_s_setprio(0);
    }
    bp += 64;
  }

  // lacc[r] = sum_k P[query = wq0+quad*4+r][k]  (same layout as o rows)
  f32x4 linv;
  for (int r = 0; r < 4; r++) linv[r] = 1.0f / lacc[r];
  for (int r = 0; r < 4; r++) {
    int qrow = wq0 + quad * 4 + r;
    unsigned short* op = attnOut + (long)qrow * DMODEL + h * HD;
    for (int jd = 0; jd < 8; jd++) op[jd * 16 + l15] = f2bf(o[jd][r] * linv[r]);
  }
}

// ---------------- launcher ----------------
extern "C" void kernel_launch(void* const* d_in, const int* in_sizes, int n_in,
                              void* d_out, int out_size, void* d_ws, size_t ws_size,
                              hipStream_t stream) {
  (void)in_sizes; (void)n_in; (void)out_size; (void)ws_size;
  const float* hidden    = (const float*)d_in[0];
  const float* sink_k    = (const float*)d_in[1];
  const float* sink_v    = (const float*)d_in[2];
  const float* win_k     = (const float*)d_in[3];
  const float* win_v     = (const float*)d_in[4];
  const int*   sink_pos  = (const int*)d_in[5];
  const int*   key_pos   = (const int*)d_in[6];
  const float* sink_mask = (const float*)d_in[7];
  const float* key_mask  = (const float*)d_in[8];
  const float* Wq = (const float*)d_in[9];
  const float* Wk = (const float*)d_in[10];
  const float* Wv = (const float*)d_in[11];
  const float* Wo = (const float*)d_in[12];
  float* out = (float*)d_out;

  char* ws = (char*)d_ws;
  unsigned short* hidB  = (unsigned short*)(ws + 0);           // 16.8 MB; attn reuses
  unsigned short* attn  = (unsigned short*)(ws + 0);
  unsigned short* WoT   = (unsigned short*)(ws + 16777216L);   // 33.5 MB
  unsigned short* WqkvT = (unsigned short*)(ws + 50331648L);   // 50.3 MB
  unsigned short* Qb    = (unsigned short*)(ws + 100663296L);  // 16.8 MB
  unsigned short* Kb    = (unsigned short*)(ws + 117440512L);  // 8.65 MB
  unsigned short* VTb   = (unsigned short*)(ws + 126091264L);  // 8.65 MB
  float2* postab        = (float2*)(ws + 134742016L);          // 1 MB
  float* bias           = (float*)(ws + 135790592L);           // 16.9 KB
  int* maxp             = (int*)(ws + 135807488L);

  maxpos_kernel<<<1, 256, 0, stream>>>(sink_pos, key_pos, maxp);
  bias_kernel<<<(KT_PAD + 255) / 256, 256, 0, stream>>>(sink_mask, key_mask, bias);
  postab_kernel<<<QLEN, 64, 0, stream>>>(maxp, postab);
  cvt_kernel<<<(QLEN * DMODEL / 4) / 256, 256, 0, stream>>>(hidden, hidB);
  transpose_all<<<dim3(320, 128), dim3(32, 8), 0, stream>>>(Wq, Wk, Wv, Wo, WqkvT, WoT);

  gemm_qkv<<<dim3(48, 16), 256, 0, stream>>>(hidB, WqkvT, postab, Qb, Kb, VTb);

  rope_cache<<<dim3(CUR0, NKV), 128, 0, stream>>>(sink_k, win_k, sink_pos, key_pos, Kb);
  scatter_cache<<<dim3(65, 4, NKV), dim3(32, 8), 0, stream>>>(sink_v, win_v, VTb);
  pad_zero<<<(NKV * (KT_PAD - KTOT) * HD + 255) / 256, 256, 0, stream>>>(Kb, VTb);

  attn_kernel<<<dim3(32, 16), 512, 0, stream>>>(Qb, Kb, VTb, bias, attn);

  gemm_bt<<<dim3(32, 16), 256, 0, stream>>>(attn, WoT, out, QLEN, DMODEL, DMODEL);
}